// Round 4
// baseline (556.831 us; speedup 1.0000x reference)
//
#include <hip/hip_runtime.h>

typedef unsigned short u16;
typedef unsigned int u32;
typedef __attribute__((ext_vector_type(8))) short bf16x8;
typedef __attribute__((ext_vector_type(4))) float f32x4;

namespace {

constexpr int S = 1024, D = 1024, H = 16, DK = 64;
constexpr float NEGF = -1e30f;

__device__ __forceinline__ u16 f2bf(float f){
  u32 u = __builtin_bit_cast(u32, f);
  u32 r = (u + 0x7fffu + ((u >> 16) & 1u)) >> 16;
  return (u16)r;
}
__device__ __forceinline__ float bf2f(u16 h){
  u32 u = ((u32)h) << 16;
  return __builtin_bit_cast(float, u);
}
__device__ __forceinline__ u32 pack2(float a, float b){
  return (u32)f2bf(a) | ((u32)f2bf(b) << 16);
}
__device__ __forceinline__ void glds16(const u16* g, u16* l){
  __builtin_amdgcn_global_load_lds(
      (const __attribute__((address_space(1))) u32*)g,
      (__attribute__((address_space(3))) u32*)l, 16, 0, 0);
}
// XOR-swizzled LDS address (u16 units). Rows are 64 elems (128B), slot = 16B chunk.
__device__ __forceinline__ int swz(int row, int slot){
  return row*64 + ((slot ^ (row & 7)) << 3);
}

// ---------------------------------------------------------------- seg scan
__global__ void seg_kernel(const int* __restrict__ ids, int* __restrict__ segd){
  __shared__ int sc[1024];
  int b = blockIdx.x, t = threadIdx.x;
  int id = ids[b*S + t];
  sc[t] = (id == 1) ? 1 : 0;
  __syncthreads();
  for(int off = 1; off < 1024; off <<= 1){
    int add = (t >= off) ? sc[t - off] : 0;
    __syncthreads();
    sc[t] += add;
    __syncthreads();
  }
  int seg = sc[t];
  segd[b*S + t] = (seg << 2) | ((id == 2) ? 2 : 0) | ((id != 0) ? 1 : 0);
}

// ---------------------------------------------------------------- layernorm
__global__ __launch_bounds__(256) void ln_kernel(const float* __restrict__ x,
    const float* __restrict__ w, const float* __restrict__ bias, u16* __restrict__ out){
  int row = blockIdx.x, t = threadIdx.x;
  float4 v = ((const float4*)(x + (size_t)row*D))[t];
  float s = v.x + v.y + v.z + v.w;
  float q = v.x*v.x + v.y*v.y + v.z*v.z + v.w*v.w;
  for(int off = 32; off >= 1; off >>= 1){ s += __shfl_down(s, off); q += __shfl_down(q, off); }
  __shared__ float ls[4], lq[4];
  int wv = t >> 6, ln = t & 63;
  if(ln == 0){ ls[wv] = s; lq[wv] = q; }
  __syncthreads();
  s = ls[0] + ls[1] + ls[2] + ls[3];
  q = lq[0] + lq[1] + lq[2] + lq[3];
  float mean = s * (1.f/D);
  float var  = q * (1.f/D) - mean*mean;
  float rs = rsqrtf(var + 1e-5f);
  float4 wv4 = ((const float4*)w)[t];
  float4 bv4 = ((const float4*)bias)[t];
  ushort4 o;
  o.x = f2bf((v.x-mean)*rs*wv4.x + bv4.x);
  o.y = f2bf((v.y-mean)*rs*wv4.y + bv4.y);
  o.z = f2bf((v.z-mean)*rs*wv4.z + bv4.z);
  o.w = f2bf((v.w-mean)*rs*wv4.w + bv4.w);
  *(ushort4*)(out + (size_t)row*D + t*4) = o;
}

// ---------------------------------------------------------------- head proj -> transposed [b,h,s]
template<bool DUAL>
__global__ __launch_bounds__(256) void headproj_kernel(const u16* __restrict__ xln,
    const float* __restrict__ wg, const float* __restrict__ bg, float* __restrict__ outg,
    const float* __restrict__ wa, float* __restrict__ outa){
  __shared__ u16 xrow[D];
  int row = blockIdx.x, t = threadIdx.x;
  ((ushort4*)xrow)[t] = ((const ushort4*)(xln + (size_t)row*D))[t];
  __syncthreads();
  int h = t >> 4, sg = t & 15;
  const u16* xp = xrow + sg*64;
  const float* wpg = wg + (size_t)h*D + sg*64;
  const float* wpa = DUAL ? (wa + (size_t)h*D + sg*64) : nullptr;
  float accg = 0.f, acca = 0.f;
  #pragma unroll
  for(int c = 0; c < 64; ++c){
    float xv = bf2f(xp[c]);
    accg += xv * wpg[c];
    if constexpr (DUAL) acca += xv * wpa[c];
  }
  for(int off = 1; off < 16; off <<= 1){
    accg += __shfl_xor(accg, off);
    if constexpr (DUAL) acca += __shfl_xor(acca, off);
  }
  if(sg == 0){
    int b = row >> 10, s = row & 1023;
    size_t oi = ((size_t)(b*H + h) << 10) + s;
    float r = accg + bg[h];
    outg[oi] = 1.f/(1.f + __expf(-r));
    if constexpr (DUAL) outa[oi] = acca;
  }
}

// ---------------------------------------------------------------- GEMM, BM=64, BK=64, swizzled LDS, 2-phase dbuf
// MODE 0: fused qkv (BN=128, 3 f32 weight mats, q pre-scaled 0.125, v transposed out)
// MODE 1: bf16 transposed out (vt);  MODE 2: f32 + resid
template<int MODE, int BN>
__global__ __launch_bounds__(256) void gemm_t(const u16* __restrict__ A,
    const float* __restrict__ W0, const float* __restrict__ W1, const float* __restrict__ W2,
    const float* __restrict__ b0f, const float* __restrict__ b1f, const float* __restrict__ b2f,
    void* __restrict__ o0, void* __restrict__ o1, void* __restrict__ o2,
    const float* __restrict__ resid){
  constexpr int K = 1024;
  constexpr int RN = BN/32;              // 2 or 4 n-frags per wave
  constexpr int BSZ = BN*64;             // Bs elems per buffer
  constexpr int NBX = (MODE == 0) ? 24 : 16;
  constexpr int CPX = (NBX*32)/8;
  __shared__ alignas(16) u16 As[2*4096];
  __shared__ alignas(16) u16 Bs[2*BSZ];
  int bid = blockIdx.x;
  int vid = (bid & 7)*CPX + (bid >> 3);
  int bx = vid / 32, by = vid % 32;
  int m0 = by*64;
  const float* W; const float* bias; int mat, n0;
  if constexpr (MODE == 0){
    mat = bx >> 3; n0 = (bx & 7)*128;
    W = (mat == 0) ? W0 : (mat == 1) ? W1 : W2;
    bias = (mat == 0) ? b0f : (mat == 1) ? b1f : b2f;
  } else { mat = 0; n0 = bx*BN; W = W0; bias = b0f; }
  int t = threadIdx.x, w = t >> 6, lane = t & 63, g = lane >> 4, l15 = lane & 15;
  int r0 = (w >> 1)*32, c0 = (w & 1)*(BN/2);
  int rl = lane >> 3, sl = lane & 7;
  int scol = ((sl ^ rl) << 3);
  f32x4 acc[2][RN] = {};
  auto STAGE = [&](int kt, int buf){
    // A (bf16): wave w stages rows w*16..w*16+15, linear LDS dest, pre-swizzled src
    const u16* ag = A + (size_t)(m0 + w*16 + rl)*K + kt*64 + scol;
    glds16(ag,               &As[buf*4096 + w*1024]);
    glds16(ag + (size_t)8*K, &As[buf*4096 + w*1024 + 512]);
    // B (f32 -> bf16): reg-stage + swizzled ds_write
    if constexpr (BN == 128){
      int row = t >> 1;
      const float* wr = W + (size_t)(n0 + row)*K + kt*64;
      #pragma unroll
      for(int j = 0; j < 4; ++j){
        int sd = (t & 1)*4 + j;
        const float* src = wr + sd*8;
        float4 x = *(const float4*)src, y = *(const float4*)(src + 4);
        u32 p[4] = { pack2(x.x,x.y), pack2(x.z,x.w), pack2(y.x,y.y), pack2(y.z,y.w) };
        *(uint4*)&Bs[buf*BSZ + swz(row, sd)] = *(uint4*)p;
      }
    } else {
      int row = t >> 2;
      const float* wr = W + (size_t)(n0 + row)*K + kt*64;
      #pragma unroll
      for(int j = 0; j < 2; ++j){
        int sd = (t & 3)*2 + j;
        const float* src = wr + sd*8;
        float4 x = *(const float4*)src, y = *(const float4*)(src + 4);
        u32 p[4] = { pack2(x.x,x.y), pack2(x.z,x.w), pack2(y.x,y.y), pack2(y.z,y.w) };
        *(uint4*)&Bs[buf*BSZ + swz(row, sd)] = *(uint4*)p;
      }
    }
  };
  STAGE(0, 0);
  asm volatile("s_waitcnt vmcnt(0)");
  __syncthreads();
  int cur = 0;
  for(int kt = 0; kt < 16; ++kt){
    if(kt + 1 < 16) STAGE(kt + 1, cur ^ 1);
    bf16x8 af[2][2], bfr[RN][2];
    #pragma unroll
    for(int m = 0; m < 2; ++m)
      #pragma unroll
      for(int ks = 0; ks < 2; ++ks)
        af[m][ks] = *(const bf16x8*)&As[cur*4096 + swz(r0 + m*16 + l15, ks*4 + g)];
    #pragma unroll
    for(int n = 0; n < RN; ++n)
      #pragma unroll
      for(int ks = 0; ks < 2; ++ks)
        bfr[n][ks] = *(const bf16x8*)&Bs[cur*BSZ + swz(c0 + n*16 + l15, ks*4 + g)];
    __builtin_amdgcn_s_setprio(1);
    #pragma unroll
    for(int ks = 0; ks < 2; ++ks)
      #pragma unroll
      for(int m = 0; m < 2; ++m)
        #pragma unroll
        for(int n = 0; n < RN; ++n)
          acc[m][n] = __builtin_amdgcn_mfma_f32_16x16x32_bf16(af[m][ks], bfr[n][ks], acc[m][n], 0, 0, 0);
    __builtin_amdgcn_s_setprio(0);
    if(kt + 1 < 16){
      asm volatile("s_waitcnt vmcnt(0)");
      __syncthreads();
      cur ^= 1;
    }
  }
  #pragma unroll
  for(int m = 0; m < 2; ++m){
    #pragma unroll
    for(int n = 0; n < RN; ++n){
      int ng = n0 + c0 + n*16 + l15;
      float bv = bias ? bias[ng] : 0.f;
      #pragma unroll
      for(int i = 0; i < 4; ++i){
        int mg = m0 + r0 + m*16 + g*4 + i;
        float v = acc[m][n][i] + bv;
        if constexpr (MODE == 0){
          if(mat == 0) v *= 0.125f;          // fold DK^-0.5 into Q
          if(mat < 2){
            u16* o = (mat == 0) ? (u16*)o0 : (u16*)o1;
            o[(size_t)mg*D + ng] = f2bf(v);
          } else {
            int b = mg >> 10, s = mg & 1023;
            ((u16*)o2)[((size_t)(b*D + ng))*S + s] = f2bf(v);
          }
        } else if constexpr (MODE == 1){
          int b = mg >> 10, s = mg & 1023;
          ((u16*)o0)[((size_t)(b*D + ng))*S + s] = f2bf(v);
        } else {
          ((float*)o0)[(size_t)mg*1024 + ng] = resid[(size_t)mg*1024 + ng] + v;
        }
      }
    }
  }
}

// ---------------------------------------------------------------- fused attention v4 (flash-block)
// block = 4 waves = one (b,h), q-rows qb*64..qb*64+63 (wave w owns q-tile qb*4+w).
// K-chunk [64k][64d] + Vt-chunk [64d][64k] staged in LDS (glds16, pre-swizzled src),
// double-buffered; every wave needs exactly qb+1 chunks -> zero waste, uniform barriers.
__device__ __forceinline__ bf16x8 repack8(const float* s, int g, int l15){
  u32 L0 = pack2(s[0], s[1]), L1 = pack2(s[2], s[3]);
  u32 H0 = pack2(s[4], s[5]), H1 = pack2(s[6], s[7]);
  int base = ((g & 1)*2)*16 + l15;
  u32 a0 = (u32)__shfl((int)L0, base),    a1 = (u32)__shfl((int)L1, base);
  u32 b0 = (u32)__shfl((int)L0, base+16), b1 = (u32)__shfl((int)L1, base+16);
  u32 c0 = (u32)__shfl((int)H0, base),    c1 = (u32)__shfl((int)H1, base);
  u32 d0 = (u32)__shfl((int)H0, base+16), d1 = (u32)__shfl((int)H1, base+16);
  bool hi = g >= 2;
  union { u32 wd[4]; bf16x8 v; } pu;
  pu.wd[0] = hi ? c0 : a0;
  pu.wd[1] = hi ? c1 : a1;
  pu.wd[2] = hi ? d0 : b0;
  pu.wd[3] = hi ? d1 : b1;
  return pu.v;
}

template<int MODE>   // 0: SDPA self; 1: SDPA cross; 2: pool self
__global__ __launch_bounds__(256) void attn4_kernel(const u16* __restrict__ Q,
    const u16* __restrict__ Kb, const u16* __restrict__ Vt,
    const float* __restrict__ aprojT, const int* __restrict__ segd,
    const float* __restrict__ gateT, u16* __restrict__ out){
  constexpr int KSZ = (MODE == 2) ? 16 : 8192;
  __shared__ alignas(16) u16 Klds[KSZ];
  __shared__ alignas(16) u16 Vlds[8192];
  __shared__ int segL[1024];
  __shared__ float apL[(MODE == 2) ? 1024 : 16];
  __shared__ u16 ot[4][16][72];
  int bid = blockIdx.x;                  // 512 blocks
  int vid = (bid & 7)*64 + (bid >> 3);   // XCD-chunked
  int bh = vid >> 4, qb = 15 - (vid & 15);   // descending qb within XCD chunk
  int b = bh >> 4, h = bh & 15;
  int t = threadIdx.x, w = t >> 6, lane = t & 63, g = lane >> 4, l15 = lane & 15;
  { int4 v = ((const int4*)(segd + b*S))[t]; *(int4*)&segL[t*4] = v; }
  if constexpr (MODE == 2){
    float4 v = ((const float4*)(aprojT + ((size_t)bh << 10)))[t];
    *(float4*)&apL[t*4] = v;
  }
  int qt = qb*4 + w, q = qt*16 + l15;
  float hs = exp2f(-(float)(h + 1) * 0.5f);
  int rl = lane >> 3, sl = lane & 7;
  int scol = ((sl ^ rl) << 3);
  bf16x8 qf0 = {}, qf1 = {};
  if constexpr (MODE != 2){
    const u16* qp = Q + ((size_t)(b*S + q))*D + h*DK + g*8;
    qf0 = *(const bf16x8*)qp;
    qf1 = *(const bf16x8*)(qp + 32);
  }
  auto STAGE = [&](int buf, int kc){
    int k0 = kc*64;
    if constexpr (MODE != 2){
      const u16* kg = Kb + (size_t)(b*S + k0 + w*16 + rl)*D + h*DK + scol;
      glds16(kg,               &Klds[buf*4096 + w*1024]);
      glds16(kg + (size_t)8*D, &Klds[buf*4096 + w*1024 + 512]);
    }
    const u16* vg = Vt + (size_t)(bh*DK + w*16 + rl)*S + k0 + scol;
    glds16(vg,               &Vlds[buf*4096 + w*1024]);
    glds16(vg + (size_t)8*S, &Vlds[buf*4096 + w*1024 + 512]);
  };

  f32x4 oacc[4] = {};
  float mrun = NEGF, lsum = 0.f;
  int sdq = 0, seg_q = 0, mq = 0;
  // segL not yet visible; read after first barrier below.

  int nc = qb + 1;
  STAGE(0, 0);
  asm volatile("s_waitcnt vmcnt(0)");
  __syncthreads();
  sdq = segL[q]; seg_q = sdq >> 2; mq = sdq & 1;

  int cur = 0;
  for(int kc = 0; kc < nc; ++kc){
    if(kc + 1 < nc) STAGE(cur ^ 1, kc + 1);
    int k0 = kc*64;
    const u16* KL = &Klds[cur*4096];
    const u16* VL = &Vlds[cur*4096];
    // V frags early (LDS ready for buf cur)
    bf16x8 vr[2][4];
    #pragma unroll
    for(int ks = 0; ks < 2; ++ks)
      #pragma unroll
      for(int c = 0; c < 4; ++c)
        vr[ks][c] = *(const bf16x8*)&VL[swz(c*16 + l15, ks*4 + g)];
    float sv[16];
    if constexpr (MODE != 2){
      __builtin_amdgcn_s_setprio(1);
      #pragma unroll
      for(int r = 0; r < 4; ++r){
        f32x4 sa = {};
        sa = __builtin_amdgcn_mfma_f32_16x16x32_bf16(
               *(const bf16x8*)&KL[swz(r*16 + l15, g)],     qf0, sa, 0, 0, 0);
        sa = __builtin_amdgcn_mfma_f32_16x16x32_bf16(
               *(const bf16x8*)&KL[swz(r*16 + l15, 4 + g)], qf1, sa, 0, 0, 0);
        #pragma unroll
        for(int i = 0; i < 4; ++i) sv[r*4+i] = sa[i];
      }
      __builtin_amdgcn_s_setprio(0);
    } else {
      #pragma unroll
      for(int r = 0; r < 4; ++r){
        float4 a4 = *(const float4*)&apL[k0 + r*16 + g*4];
        sv[r*4+0] = a4.x; sv[r*4+1] = a4.y; sv[r*4+2] = a4.z; sv[r*4+3] = a4.w;
      }
    }
    #pragma unroll
    for(int r = 0; r < 4; ++r){
      int4 sd4 = *(const int4*)&segL[k0 + r*16 + g*4];
      int sds[4] = { sd4.x, sd4.y, sd4.z, sd4.w };
      #pragma unroll
      for(int i = 0; i < 4; ++i){
        int key = k0 + r*16 + g*4 + i;
        int sdk = sds[i];
        bool ok; float val;
        if constexpr (MODE == 1){
          ok = (key < q && (sdk & 2)) || (key == q);
          val = (float)((sdk >> 2) - seg_q);
        } else {
          ok = (key < q && ((sdk >> 2) == seg_q) && (sdk & mq & 1)) || (key == q);
          val = (float)(key - q);
        }
        sv[r*4+i] = ok ? sv[r*4+i] + val*hs : NEGF;
      }
    }
    float cm = sv[0];
    #pragma unroll
    for(int i = 1; i < 16; ++i) cm = fmaxf(cm, sv[i]);
    cm = fmaxf(cm, __shfl_xor(cm, 16));
    cm = fmaxf(cm, __shfl_xor(cm, 32));
    float mnew = fmaxf(mrun, cm);
    float fac = __expf(mrun - mnew);
    float ps = 0.f;
    #pragma unroll
    for(int i = 0; i < 16; ++i){ sv[i] = __expf(sv[i] - mnew); ps += sv[i]; }
    ps += __shfl_xor(ps, 16);
    ps += __shfl_xor(ps, 32);
    lsum = lsum * fac + ps;
    mrun = mnew;
    #pragma unroll
    for(int c = 0; c < 4; ++c)
      #pragma unroll
      for(int i = 0; i < 4; ++i) oacc[c][i] *= fac;
    __builtin_amdgcn_s_setprio(1);
    #pragma unroll
    for(int ks = 0; ks < 2; ++ks){
      bf16x8 pf = repack8(&sv[ks*8], g, l15);
      #pragma unroll
      for(int c = 0; c < 4; ++c)
        oacc[c] = __builtin_amdgcn_mfma_f32_16x16x32_bf16(vr[ks][c], pf, oacc[c], 0, 0, 0);
    }
    __builtin_amdgcn_s_setprio(0);
    if(kc + 1 < nc){
      asm volatile("s_waitcnt vmcnt(0)");
      __syncthreads();
      cur ^= 1;
    }
  }

  float scale = (1.f / lsum) * gateT[((size_t)bh << 10) + q];
  #pragma unroll
  for(int c = 0; c < 4; ++c)
    #pragma unroll
    for(int i = 0; i < 4; i += 2){
      u32 p = pack2(oacc[c][i]*scale, oacc[c][i+1]*scale);
      *(u32*)&ot[w][l15][c*16 + g*4 + i] = p;
    }
  int r = lane >> 2, c4 = lane & 3;
  uint4 v0 = *(uint4*)&ot[w][r][c4*16];
  uint4 v1 = *(uint4*)&ot[w][r][c4*16 + 8];
  u16* op = out + ((size_t)(b*S + qt*16 + r))*D + h*DK + c4*16;
  *(uint4*)op = v0;
  *(uint4*)(op + 8) = v1;
}

} // namespace

extern "C" void kernel_launch(void* const* d_in, const int* in_sizes, int n_in,
                              void* d_out, int out_size, void* d_ws, size_t ws_size,
                              hipStream_t stream){
  (void)in_sizes; (void)n_in; (void)out_size; (void)ws_size;
  const float* states = (const float*)d_in[0];
  const int*   ids    = (const int*)d_in[1];
  float* xout = (float*)d_out;

  char* w = (char*)d_ws;
  u16* xln  = (u16*)w; w += (size_t)2048*1024*2;
  u16* qb   = (u16*)w; w += (size_t)2048*1024*2;
  u16* kb   = (u16*)w; w += (size_t)2048*1024*2;
  u16* vt   = (u16*)w; w += (size_t)2048*1024*2;
  u16* attn = (u16*)w; w += (size_t)2048*1024*2;
  float* gateT  = (float*)w; w += (size_t)2048*16*4;
  float* aprojT = (float*)w; w += (size_t)2048*16*4;
  int* segd = (int*)w;

  seg_kernel<<<dim3(2), dim3(1024), 0, stream>>>(ids, segd);

  dim3 b256(256), g2048(2048);
  dim3 gqkv(768), ggen(512), gattn(512);

  // ---- layer 0: SDPA, self bias
  ln_kernel<<<g2048, b256, 0, stream>>>(states, (const float*)d_in[2], (const float*)d_in[3], xln);
  gemm_t<0,128><<<gqkv, b256, 0, stream>>>(xln, (const float*)d_in[4], (const float*)d_in[6], (const float*)d_in[8],
      (const float*)d_in[5], (const float*)d_in[7], (const float*)d_in[9], qb, kb, vt, nullptr);
  headproj_kernel<false><<<g2048, b256, 0, stream>>>(xln, (const float*)d_in[10], (const float*)d_in[11], gateT, nullptr, nullptr);
  attn4_kernel<0><<<gattn, b256, 0, stream>>>(qb, kb, vt, nullptr, segd, gateT, attn);
  gemm_t<2,64><<<ggen, b256, 0, stream>>>(attn, (const float*)d_in[12], nullptr, nullptr,
      (const float*)d_in[13], nullptr, nullptr, xout, nullptr, nullptr, states);

  // ---- layer 1: pool, self bias
  ln_kernel<<<g2048, b256, 0, stream>>>(xout, (const float*)d_in[14], (const float*)d_in[15], xln);
  gemm_t<1,64><<<ggen, b256, 0, stream>>>(xln, (const float*)d_in[17], nullptr, nullptr,
      (const float*)d_in[18], nullptr, nullptr, vt, nullptr, nullptr, nullptr);
  headproj_kernel<true><<<g2048, b256, 0, stream>>>(xln, (const float*)d_in[19], (const float*)d_in[20], gateT,
      (const float*)d_in[16], aprojT);
  attn4_kernel<2><<<gattn, b256, 0, stream>>>(nullptr, nullptr, vt, aprojT, segd, gateT, attn);
  gemm_t<2,64><<<ggen, b256, 0, stream>>>(attn, (const float*)d_in[21], nullptr, nullptr,
      (const float*)d_in[22], nullptr, nullptr, xout, nullptr, nullptr, xout);

  // ---- layer 2: SDPA, cross bias
  ln_kernel<<<g2048, b256, 0, stream>>>(xout, (const float*)d_in[23], (const float*)d_in[24], xln);
  gemm_t<0,128><<<gqkv, b256, 0, stream>>>(xln, (const float*)d_in[25], (const float*)d_in[27], (const float*)d_in[29],
      (const float*)d_in[26], (const float*)d_in[28], (const float*)d_in[30], qb, kb, vt, nullptr);
  headproj_kernel<false><<<g2048, b256, 0, stream>>>(xln, (const float*)d_in[31], (const float*)d_in[32], gateT, nullptr, nullptr);
  attn4_kernel<1><<<gattn, b256, 0, stream>>>(qb, kb, vt, nullptr, segd, gateT, attn);
  gemm_t<2,64><<<ggen, b256, 0, stream>>>(attn, (const float*)d_in[33], nullptr, nullptr,
      (const float*)d_in[34], nullptr, nullptr, xout, nullptr, nullptr, xout);
}

// Round 5
// 497.054 us; speedup vs baseline: 1.1203x; 1.1203x over previous
//
#include <hip/hip_runtime.h>

typedef unsigned short u16;
typedef unsigned int u32;
typedef __attribute__((ext_vector_type(8))) short bf16x8;
typedef __attribute__((ext_vector_type(4))) float f32x4;

namespace {

constexpr int S = 1024, D = 1024, H = 16, DK = 64;
constexpr float NEGF = -1e30f;

__device__ __forceinline__ u16 f2bf(float f){
  u32 u = __builtin_bit_cast(u32, f);
  u32 r = (u + 0x7fffu + ((u >> 16) & 1u)) >> 16;
  return (u16)r;
}
__device__ __forceinline__ float bf2f(u16 h){
  u32 u = ((u32)h) << 16;
  return __builtin_bit_cast(float, u);
}
__device__ __forceinline__ u32 pack2(float a, float b){
  return (u32)f2bf(a) | ((u32)f2bf(b) << 16);
}
__device__ __forceinline__ void glds16(const u16* g, u16* l){
  __builtin_amdgcn_global_load_lds(
      (const __attribute__((address_space(1))) u32*)g,
      (__attribute__((address_space(3))) u32*)l, 16, 0, 0);
}
// XOR-swizzled LDS address (u16 units). Rows are 64 elems (128B), slot = 16B chunk.
__device__ __forceinline__ int swz(int row, int slot){
  return row*64 + ((slot ^ (row & 7)) << 3);
}

// ---------------------------------------------------------------- weight f32->bf16
struct CvtArgs { const float* src[10]; u16* dst[10]; };
__global__ __launch_bounds__(256) void cvt_kernel(CvtArgs a){
  int m = blockIdx.y;
  const float* s = a.src[m];
  u16* d = a.dst[m];
  int i = (blockIdx.x * 256 + threadIdx.x) * 8;
  float4 v0 = *(const float4*)(s + i), v1 = *(const float4*)(s + i + 4);
  u32 p[4] = { pack2(v0.x,v0.y), pack2(v0.z,v0.w), pack2(v1.x,v1.y), pack2(v1.z,v1.w) };
  *(uint4*)(d + i) = *(uint4*)p;
}

// ---------------------------------------------------------------- seg scan
__global__ void seg_kernel(const int* __restrict__ ids, int* __restrict__ segd){
  __shared__ int sc[1024];
  int b = blockIdx.x, t = threadIdx.x;
  int id = ids[b*S + t];
  sc[t] = (id == 1) ? 1 : 0;
  __syncthreads();
  for(int off = 1; off < 1024; off <<= 1){
    int add = (t >= off) ? sc[t - off] : 0;
    __syncthreads();
    sc[t] += add;
    __syncthreads();
  }
  int seg = sc[t];
  segd[b*S + t] = (seg << 2) | ((id == 2) ? 2 : 0) | ((id != 0) ? 1 : 0);
}

// ---------------------------------------------------------------- layernorm
__global__ __launch_bounds__(256) void ln_kernel(const float* __restrict__ x,
    const float* __restrict__ w, const float* __restrict__ bias, u16* __restrict__ out){
  int row = blockIdx.x, t = threadIdx.x;
  float4 v = ((const float4*)(x + (size_t)row*D))[t];
  float s = v.x + v.y + v.z + v.w;
  float q = v.x*v.x + v.y*v.y + v.z*v.z + v.w*v.w;
  for(int off = 32; off >= 1; off >>= 1){ s += __shfl_down(s, off); q += __shfl_down(q, off); }
  __shared__ float ls[4], lq[4];
  int wv = t >> 6, ln = t & 63;
  if(ln == 0){ ls[wv] = s; lq[wv] = q; }
  __syncthreads();
  s = ls[0] + ls[1] + ls[2] + ls[3];
  q = lq[0] + lq[1] + lq[2] + lq[3];
  float mean = s * (1.f/D);
  float var  = q * (1.f/D) - mean*mean;
  float rs = rsqrtf(var + 1e-5f);
  float4 wv4 = ((const float4*)w)[t];
  float4 bv4 = ((const float4*)bias)[t];
  ushort4 o;
  o.x = f2bf((v.x-mean)*rs*wv4.x + bv4.x);
  o.y = f2bf((v.y-mean)*rs*wv4.y + bv4.y);
  o.z = f2bf((v.z-mean)*rs*wv4.z + bv4.z);
  o.w = f2bf((v.w-mean)*rs*wv4.w + bv4.w);
  *(ushort4*)(out + (size_t)row*D + t*4) = o;
}

// ---------------------------------------------------------------- head proj -> transposed [b,h,s]
template<bool DUAL>
__global__ __launch_bounds__(256) void headproj_kernel(const u16* __restrict__ xln,
    const float* __restrict__ wg, const float* __restrict__ bg, float* __restrict__ outg,
    const float* __restrict__ wa, float* __restrict__ outa){
  __shared__ u16 xrow[D];
  int row = blockIdx.x, t = threadIdx.x;
  ((ushort4*)xrow)[t] = ((const ushort4*)(xln + (size_t)row*D))[t];
  __syncthreads();
  int h = t >> 4, sg = t & 15;
  const u16* xp = xrow + sg*64;
  const float* wpg = wg + (size_t)h*D + sg*64;
  const float* wpa = DUAL ? (wa + (size_t)h*D + sg*64) : nullptr;
  float accg = 0.f, acca = 0.f;
  #pragma unroll
  for(int c = 0; c < 64; ++c){
    float xv = bf2f(xp[c]);
    accg += xv * wpg[c];
    if constexpr (DUAL) acca += xv * wpa[c];
  }
  for(int off = 1; off < 16; off <<= 1){
    accg += __shfl_xor(accg, off);
    if constexpr (DUAL) acca += __shfl_xor(acca, off);
  }
  if(sg == 0){
    int b = row >> 10, s = row & 1023;
    size_t oi = ((size_t)(b*H + h) << 10) + s;
    float r = accg + bg[h];
    outg[oi] = 1.f/(1.f + __expf(-r));
    if constexpr (DUAL) outa[oi] = acca;
  }
}

// ---------------------------------------------------------------- GEMM v5: bf16 both operands, glds16, BK=64,
// swizzled LDS, 2-phase dbuf, 64x64 wave tiles (MFMA:ds_read = 2:1).
// MODE 0: fused qkv (BN=128, q pre-scaled 0.125, v transposed out)
// MODE 1: bf16 transposed out (vt);  MODE 2: f32 + resid
template<int MODE, int BM, int BN>
__global__ __launch_bounds__(256) void gemm_t(const u16* __restrict__ A,
    const u16* __restrict__ W0, const u16* __restrict__ W1, const u16* __restrict__ W2,
    const float* __restrict__ b0f, const float* __restrict__ b1f, const float* __restrict__ b2f,
    void* __restrict__ o0, void* __restrict__ o1, void* __restrict__ o2,
    const float* __restrict__ resid){
  constexpr int K = 1024;
  constexpr int RM = BM/32, RN = BN/32;        // frags per wave (2x2 wave grid)
  constexpr int NBY = 2048/BM;
  constexpr int NBX = ((MODE == 0) ? 3072 : 1024)/BN;
  constexpr int CPX = (NBX*NBY)/8;
  __shared__ alignas(16) u16 As[2*BM*64];
  __shared__ alignas(16) u16 Bs[2*BN*64];
  int bid = blockIdx.x;
  int vid = (bid & 7)*CPX + (bid >> 3);        // XCD-chunked, bijective (grid%8==0)
  int bx = vid / NBY, by = vid % NBY;          // consecutive vids share W panel
  int m0 = by*BM;
  const u16* W; const float* bias; int mat, n0;
  if constexpr (MODE == 0){
    mat = bx >> 3; n0 = (bx & 7)*BN;
    W = (mat == 0) ? W0 : (mat == 1) ? W1 : W2;
    bias = (mat == 0) ? b0f : (mat == 1) ? b1f : b2f;
  } else { mat = 0; n0 = bx*BN; W = W0; bias = b0f; }
  int t = threadIdx.x, w = t >> 6, lane = t & 63, g = lane >> 4, l15 = lane & 15;
  int wr = w >> 1, wc = w & 1;
  int rl = lane >> 3, sl = lane & 7;
  int scol = ((sl ^ rl) << 3);                 // inverse-swizzled global col
  f32x4 acc[RM][RN] = {};
  const u16* ag = A + (size_t)(m0 + rl)*K + scol;
  const u16* wg = W + (size_t)(n0 + rl)*K + scol;
  auto STAGE = [&](int kt, int buf){
    #pragma unroll
    for(int j = 0; j < BM/32; ++j){
      int r = w*(BM/4) + j*8;
      glds16(ag + (size_t)r*K + kt*64, &As[buf*BM*64 + r*64]);
    }
    #pragma unroll
    for(int j = 0; j < BN/32; ++j){
      int r = w*(BN/4) + j*8;
      glds16(wg + (size_t)r*K + kt*64, &Bs[buf*BN*64 + r*64]);
    }
  };
  STAGE(0, 0);
  asm volatile("s_waitcnt vmcnt(0)");
  __syncthreads();
  int cur = 0;
  for(int kt = 0; kt < 16; ++kt){
    if(kt + 1 < 16) STAGE(kt + 1, cur ^ 1);
    bf16x8 af[RM][2], bfr[RN][2];
    #pragma unroll
    for(int m = 0; m < RM; ++m)
      #pragma unroll
      for(int ks = 0; ks < 2; ++ks)
        af[m][ks] = *(const bf16x8*)&As[cur*BM*64 + swz(wr*(BM/2) + m*16 + l15, ks*4 + g)];
    #pragma unroll
    for(int n = 0; n < RN; ++n)
      #pragma unroll
      for(int ks = 0; ks < 2; ++ks)
        bfr[n][ks] = *(const bf16x8*)&Bs[cur*BN*64 + swz(wc*(BN/2) + n*16 + l15, ks*4 + g)];
    __builtin_amdgcn_s_setprio(1);
    #pragma unroll
    for(int ks = 0; ks < 2; ++ks)
      #pragma unroll
      for(int m = 0; m < RM; ++m)
        #pragma unroll
        for(int n = 0; n < RN; ++n)
          acc[m][n] = __builtin_amdgcn_mfma_f32_16x16x32_bf16(af[m][ks], bfr[n][ks], acc[m][n], 0, 0, 0);
    __builtin_amdgcn_s_setprio(0);
    if(kt + 1 < 16){
      asm volatile("s_waitcnt vmcnt(0)");
      __syncthreads();
      cur ^= 1;
    }
  }
  #pragma unroll
  for(int m = 0; m < RM; ++m){
    #pragma unroll
    for(int n = 0; n < RN; ++n){
      int ng = n0 + wc*(BN/2) + n*16 + l15;
      float bv = bias ? bias[ng] : 0.f;
      #pragma unroll
      for(int i = 0; i < 4; ++i){
        int mg = m0 + wr*(BM/2) + m*16 + g*4 + i;
        float v = acc[m][n][i] + bv;
        if constexpr (MODE == 0){
          if(mat == 0) v *= 0.125f;          // fold DK^-0.5 into Q
          if(mat < 2){
            u16* o = (mat == 0) ? (u16*)o0 : (u16*)o1;
            o[(size_t)mg*D + ng] = f2bf(v);
          } else {
            int b = mg >> 10, s = mg & 1023;
            ((u16*)o2)[((size_t)(b*D + ng))*S + s] = f2bf(v);
          }
        } else if constexpr (MODE == 1){
          int b = mg >> 10, s = mg & 1023;
          ((u16*)o0)[((size_t)(b*D + ng))*S + s] = f2bf(v);
        } else {
          ((float*)o0)[(size_t)mg*1024 + ng] = resid[(size_t)mg*1024 + ng] + v;
        }
      }
    }
  }
}

// ---------------------------------------------------------------- fused attention v4 (flash-block) — unchanged
__device__ __forceinline__ bf16x8 repack8(const float* s, int g, int l15){
  u32 L0 = pack2(s[0], s[1]), L1 = pack2(s[2], s[3]);
  u32 H0 = pack2(s[4], s[5]), H1 = pack2(s[6], s[7]);
  int base = ((g & 1)*2)*16 + l15;
  u32 a0 = (u32)__shfl((int)L0, base),    a1 = (u32)__shfl((int)L1, base);
  u32 b0 = (u32)__shfl((int)L0, base+16), b1 = (u32)__shfl((int)L1, base+16);
  u32 c0 = (u32)__shfl((int)H0, base),    c1 = (u32)__shfl((int)H1, base);
  u32 d0 = (u32)__shfl((int)H0, base+16), d1 = (u32)__shfl((int)H1, base+16);
  bool hi = g >= 2;
  union { u32 wd[4]; bf16x8 v; } pu;
  pu.wd[0] = hi ? c0 : a0;
  pu.wd[1] = hi ? c1 : a1;
  pu.wd[2] = hi ? d0 : b0;
  pu.wd[3] = hi ? d1 : b1;
  return pu.v;
}

template<int MODE>   // 0: SDPA self; 1: SDPA cross; 2: pool self
__global__ __launch_bounds__(256) void attn4_kernel(const u16* __restrict__ Q,
    const u16* __restrict__ Kb, const u16* __restrict__ Vt,
    const float* __restrict__ aprojT, const int* __restrict__ segd,
    const float* __restrict__ gateT, u16* __restrict__ out){
  constexpr int KSZ = (MODE == 2) ? 16 : 8192;
  __shared__ alignas(16) u16 Klds[KSZ];
  __shared__ alignas(16) u16 Vlds[8192];
  __shared__ int segL[1024];
  __shared__ float apL[(MODE == 2) ? 1024 : 16];
  __shared__ u16 ot[4][16][72];
  int bid = blockIdx.x;                  // 512 blocks
  int vid = (bid & 7)*64 + (bid >> 3);   // XCD-chunked
  int bh = vid >> 4, qb = 15 - (vid & 15);   // descending qb within XCD chunk
  int b = bh >> 4, h = bh & 15;
  int t = threadIdx.x, w = t >> 6, lane = t & 63, g = lane >> 4, l15 = lane & 15;
  { int4 v = ((const int4*)(segd + b*S))[t]; *(int4*)&segL[t*4] = v; }
  if constexpr (MODE == 2){
    float4 v = ((const float4*)(aprojT + ((size_t)bh << 10)))[t];
    *(float4*)&apL[t*4] = v;
  }
  int qt = qb*4 + w, q = qt*16 + l15;
  float hs = exp2f(-(float)(h + 1) * 0.5f);
  int rl = lane >> 3, sl = lane & 7;
  int scol = ((sl ^ rl) << 3);
  bf16x8 qf0 = {}, qf1 = {};
  if constexpr (MODE != 2){
    const u16* qp = Q + ((size_t)(b*S + q))*D + h*DK + g*8;
    qf0 = *(const bf16x8*)qp;
    qf1 = *(const bf16x8*)(qp + 32);
  }
  auto STAGE = [&](int buf, int kc){
    int k0 = kc*64;
    if constexpr (MODE != 2){
      const u16* kg = Kb + (size_t)(b*S + k0 + w*16 + rl)*D + h*DK + scol;
      glds16(kg,               &Klds[buf*4096 + w*1024]);
      glds16(kg + (size_t)8*D, &Klds[buf*4096 + w*1024 + 512]);
    }
    const u16* vg = Vt + (size_t)(bh*DK + w*16 + rl)*S + k0 + scol;
    glds16(vg,               &Vlds[buf*4096 + w*1024]);
    glds16(vg + (size_t)8*S, &Vlds[buf*4096 + w*1024 + 512]);
  };

  f32x4 oacc[4] = {};
  float mrun = NEGF, lsum = 0.f;
  int sdq = 0, seg_q = 0, mq = 0;

  int nc = qb + 1;
  STAGE(0, 0);
  asm volatile("s_waitcnt vmcnt(0)");
  __syncthreads();
  sdq = segL[q]; seg_q = sdq >> 2; mq = sdq & 1;

  int cur = 0;
  for(int kc = 0; kc < nc; ++kc){
    if(kc + 1 < nc) STAGE(cur ^ 1, kc + 1);
    int k0 = kc*64;
    const u16* KL = &Klds[cur*4096];
    const u16* VL = &Vlds[cur*4096];
    bf16x8 vr[2][4];
    #pragma unroll
    for(int ks = 0; ks < 2; ++ks)
      #pragma unroll
      for(int c = 0; c < 4; ++c)
        vr[ks][c] = *(const bf16x8*)&VL[swz(c*16 + l15, ks*4 + g)];
    float sv[16];
    if constexpr (MODE != 2){
      __builtin_amdgcn_s_setprio(1);
      #pragma unroll
      for(int r = 0; r < 4; ++r){
        f32x4 sa = {};
        sa = __builtin_amdgcn_mfma_f32_16x16x32_bf16(
               *(const bf16x8*)&KL[swz(r*16 + l15, g)],     qf0, sa, 0, 0, 0);
        sa = __builtin_amdgcn_mfma_f32_16x16x32_bf16(
               *(const bf16x8*)&KL[swz(r*16 + l15, 4 + g)], qf1, sa, 0, 0, 0);
        #pragma unroll
        for(int i = 0; i < 4; ++i) sv[r*4+i] = sa[i];
      }
      __builtin_amdgcn_s_setprio(0);
    } else {
      #pragma unroll
      for(int r = 0; r < 4; ++r){
        float4 a4 = *(const float4*)&apL[k0 + r*16 + g*4];
        sv[r*4+0] = a4.x; sv[r*4+1] = a4.y; sv[r*4+2] = a4.z; sv[r*4+3] = a4.w;
      }
    }
    #pragma unroll
    for(int r = 0; r < 4; ++r){
      int4 sd4 = *(const int4*)&segL[k0 + r*16 + g*4];
      int sds[4] = { sd4.x, sd4.y, sd4.z, sd4.w };
      #pragma unroll
      for(int i = 0; i < 4; ++i){
        int key = k0 + r*16 + g*4 + i;
        int sdk = sds[i];
        bool ok; float val;
        if constexpr (MODE == 1){
          ok = (key < q && (sdk & 2)) || (key == q);
          val = (float)((sdk >> 2) - seg_q);
        } else {
          ok = (key < q && ((sdk >> 2) == seg_q) && (sdk & mq & 1)) || (key == q);
          val = (float)(key - q);
        }
        sv[r*4+i] = ok ? sv[r*4+i] + val*hs : NEGF;
      }
    }
    float cm = sv[0];
    #pragma unroll
    for(int i = 1; i < 16; ++i) cm = fmaxf(cm, sv[i]);
    cm = fmaxf(cm, __shfl_xor(cm, 16));
    cm = fmaxf(cm, __shfl_xor(cm, 32));
    float mnew = fmaxf(mrun, cm);
    float fac = __expf(mrun - mnew);
    float ps = 0.f;
    #pragma unroll
    for(int i = 0; i < 16; ++i){ sv[i] = __expf(sv[i] - mnew); ps += sv[i]; }
    ps += __shfl_xor(ps, 16);
    ps += __shfl_xor(ps, 32);
    lsum = lsum * fac + ps;
    mrun = mnew;
    #pragma unroll
    for(int c = 0; c < 4; ++c)
      #pragma unroll
      for(int i = 0; i < 4; ++i) oacc[c][i] *= fac;
    __builtin_amdgcn_s_setprio(1);
    #pragma unroll
    for(int ks = 0; ks < 2; ++ks){
      bf16x8 pf = repack8(&sv[ks*8], g, l15);
      #pragma unroll
      for(int c = 0; c < 4; ++c)
        oacc[c] = __builtin_amdgcn_mfma_f32_16x16x32_bf16(vr[ks][c], pf, oacc[c], 0, 0, 0);
    }
    __builtin_amdgcn_s_setprio(0);
    if(kc + 1 < nc){
      asm volatile("s_waitcnt vmcnt(0)");
      __syncthreads();
      cur ^= 1;
    }
  }

  float scale = (1.f / lsum) * gateT[((size_t)bh << 10) + q];
  #pragma unroll
  for(int c = 0; c < 4; ++c)
    #pragma unroll
    for(int i = 0; i < 4; i += 2){
      u32 p = pack2(oacc[c][i]*scale, oacc[c][i+1]*scale);
      *(u32*)&ot[w][l15][c*16 + g*4 + i] = p;
    }
  int r = lane >> 2, c4 = lane & 3;
  uint4 v0 = *(uint4*)&ot[w][r][c4*16];
  uint4 v1 = *(uint4*)&ot[w][r][c4*16 + 8];
  u16* op = out + ((size_t)(b*S + qt*16 + r))*D + h*DK + c4*16;
  *(uint4*)op = v0;
  *(uint4*)(op + 8) = v1;
}

} // namespace

extern "C" void kernel_launch(void* const* d_in, const int* in_sizes, int n_in,
                              void* d_out, int out_size, void* d_ws, size_t ws_size,
                              hipStream_t stream){
  (void)in_sizes; (void)n_in; (void)out_size; (void)ws_size;
  const float* states = (const float*)d_in[0];
  const int*   ids    = (const int*)d_in[1];
  float* xout = (float*)d_out;

  char* w = (char*)d_ws;
  u16* wbf[10];
  for(int i = 0; i < 10; ++i){ wbf[i] = (u16*)w; w += (size_t)1024*1024*2; }
  u16* xln  = (u16*)w; w += (size_t)2048*1024*2;
  u16* qb   = (u16*)w; w += (size_t)2048*1024*2;
  u16* kb   = (u16*)w; w += (size_t)2048*1024*2;
  u16* vt   = (u16*)w; w += (size_t)2048*1024*2;
  u16* attn = (u16*)w; w += (size_t)2048*1024*2;
  float* gateT  = (float*)w; w += (size_t)2048*16*4;
  float* aprojT = (float*)w; w += (size_t)2048*16*4;
  int* segd = (int*)w;

  // weight indices: l0 qw4 kw6 vw8 ow12 | l1 vw17 ow21 | l2 qw25 kw27 vw29 ow33
  const int widx[10] = {4, 6, 8, 12, 17, 21, 25, 27, 29, 33};
  CvtArgs ca;
  for(int i = 0; i < 10; ++i){ ca.src[i] = (const float*)d_in[widx[i]]; ca.dst[i] = wbf[i]; }
  cvt_kernel<<<dim3(512, 10), dim3(256), 0, stream>>>(ca);
  seg_kernel<<<dim3(2), dim3(1024), 0, stream>>>(ids, segd);

  dim3 b256(256), g2048(2048);
  dim3 gqkv(384), ggen(256), gattn(512);

  // ---- layer 0: SDPA, self bias
  ln_kernel<<<g2048, b256, 0, stream>>>(states, (const float*)d_in[2], (const float*)d_in[3], xln);
  gemm_t<0,128,128><<<gqkv, b256, 0, stream>>>(xln, wbf[0], wbf[1], wbf[2],
      (const float*)d_in[5], (const float*)d_in[7], (const float*)d_in[9], qb, kb, vt, nullptr);
  headproj_kernel<false><<<g2048, b256, 0, stream>>>(xln, (const float*)d_in[10], (const float*)d_in[11], gateT, nullptr, nullptr);
  attn4_kernel<0><<<gattn, b256, 0, stream>>>(qb, kb, vt, nullptr, segd, gateT, attn);
  gemm_t<2,128,64><<<ggen, b256, 0, stream>>>(attn, wbf[3], nullptr, nullptr,
      (const float*)d_in[13], nullptr, nullptr, xout, nullptr, nullptr, states);

  // ---- layer 1: pool, self bias
  ln_kernel<<<g2048, b256, 0, stream>>>(xout, (const float*)d_in[14], (const float*)d_in[15], xln);
  gemm_t<1,128,64><<<ggen, b256, 0, stream>>>(xln, wbf[4], nullptr, nullptr,
      (const float*)d_in[18], nullptr, nullptr, vt, nullptr, nullptr, nullptr);
  headproj_kernel<true><<<g2048, b256, 0, stream>>>(xln, (const float*)d_in[19], (const float*)d_in[20], gateT,
      (const float*)d_in[16], aprojT);
  attn4_kernel<2><<<gattn, b256, 0, stream>>>(nullptr, nullptr, vt, aprojT, segd, gateT, attn);
  gemm_t<2,128,64><<<ggen, b256, 0, stream>>>(attn, wbf[5], nullptr, nullptr,
      (const float*)d_in[22], nullptr, nullptr, xout, nullptr, nullptr, xout);

  // ---- layer 2: SDPA, cross bias
  ln_kernel<<<g2048, b256, 0, stream>>>(xout, (const float*)d_in[23], (const float*)d_in[24], xln);
  gemm_t<0,128,128><<<gqkv, b256, 0, stream>>>(xln, wbf[6], wbf[7], wbf[8],
      (const float*)d_in[26], (const float*)d_in[28], (const float*)d_in[30], qb, kb, vt, nullptr);
  headproj_kernel<false><<<g2048, b256, 0, stream>>>(xln, (const float*)d_in[31], (const float*)d_in[32], gateT, nullptr, nullptr);
  attn4_kernel<1><<<gattn, b256, 0, stream>>>(qb, kb, vt, nullptr, segd, gateT, attn);
  gemm_t<2,128,64><<<ggen, b256, 0, stream>>>(attn, wbf[9], nullptr, nullptr,
      (const float*)d_in[34], nullptr, nullptr, xout, nullptr, nullptr, xout);
}

// Round 6
// 420.471 us; speedup vs baseline: 1.3243x; 1.1821x over previous
//
#include <hip/hip_runtime.h>

typedef unsigned short u16;
typedef unsigned int u32;
typedef __attribute__((ext_vector_type(8))) short bf16x8;
typedef __attribute__((ext_vector_type(4))) float f32x4;

namespace {

constexpr int S = 1024, D = 1024, H = 16, DK = 64;
constexpr float NEGF = -1e30f;

__device__ __forceinline__ u16 f2bf(float f){
  u32 u = __builtin_bit_cast(u32, f);
  u32 r = (u + 0x7fffu + ((u >> 16) & 1u)) >> 16;
  return (u16)r;
}
__device__ __forceinline__ float bf2f(u16 h){
  u32 u = ((u32)h) << 16;
  return __builtin_bit_cast(float, u);
}
__device__ __forceinline__ u32 pack2(float a, float b){
  return (u32)f2bf(a) | ((u32)f2bf(b) << 16);
}
__device__ __forceinline__ void glds16(const u16* g, u16* l){
  __builtin_amdgcn_global_load_lds(
      (const __attribute__((address_space(1))) u32*)g,
      (__attribute__((address_space(3))) u32*)l, 16, 0, 0);
}
// XOR-swizzled LDS address (u16 units). Rows are 64 elems (128B), slot = 16B chunk.
__device__ __forceinline__ int swz(int row, int slot){
  return row*64 + ((slot ^ (row & 7)) << 3);
}

// ---------------------------------------------------------------- weight f32->bf16
struct CvtArgs { const float* src[10]; u16* dst[10]; };
__global__ __launch_bounds__(256) void cvt_kernel(CvtArgs a){
  int m = blockIdx.y;
  const float* s = a.src[m];
  u16* d = a.dst[m];
  int i = (blockIdx.x * 256 + threadIdx.x) * 8;
  float4 v0 = *(const float4*)(s + i), v1 = *(const float4*)(s + i + 4);
  u32 p[4] = { pack2(v0.x,v0.y), pack2(v0.z,v0.w), pack2(v1.x,v1.y), pack2(v1.z,v1.w) };
  *(uint4*)(d + i) = *(uint4*)p;
}

// ---------------------------------------------------------------- seg scan
__global__ void seg_kernel(const int* __restrict__ ids, int* __restrict__ segd){
  __shared__ int sc[1024];
  int b = blockIdx.x, t = threadIdx.x;
  int id = ids[b*S + t];
  sc[t] = (id == 1) ? 1 : 0;
  __syncthreads();
  for(int off = 1; off < 1024; off <<= 1){
    int add = (t >= off) ? sc[t - off] : 0;
    __syncthreads();
    sc[t] += add;
    __syncthreads();
  }
  int seg = sc[t];
  segd[b*S + t] = (seg << 2) | ((id == 2) ? 2 : 0) | ((id != 0) ? 1 : 0);
}

// ---------------------------------------------------------------- layernorm
__global__ __launch_bounds__(256) void ln_kernel(const float* __restrict__ x,
    const float* __restrict__ w, const float* __restrict__ bias, u16* __restrict__ out){
  int row = blockIdx.x, t = threadIdx.x;
  float4 v = ((const float4*)(x + (size_t)row*D))[t];
  float s = v.x + v.y + v.z + v.w;
  float q = v.x*v.x + v.y*v.y + v.z*v.z + v.w*v.w;
  for(int off = 32; off >= 1; off >>= 1){ s += __shfl_down(s, off); q += __shfl_down(q, off); }
  __shared__ float ls[4], lq[4];
  int wv = t >> 6, ln = t & 63;
  if(ln == 0){ ls[wv] = s; lq[wv] = q; }
  __syncthreads();
  s = ls[0] + ls[1] + ls[2] + ls[3];
  q = lq[0] + lq[1] + lq[2] + lq[3];
  float mean = s * (1.f/D);
  float var  = q * (1.f/D) - mean*mean;
  float rs = rsqrtf(var + 1e-5f);
  float4 wv4 = ((const float4*)w)[t];
  float4 bv4 = ((const float4*)bias)[t];
  ushort4 o;
  o.x = f2bf((v.x-mean)*rs*wv4.x + bv4.x);
  o.y = f2bf((v.y-mean)*rs*wv4.y + bv4.y);
  o.z = f2bf((v.z-mean)*rs*wv4.z + bv4.z);
  o.w = f2bf((v.w-mean)*rs*wv4.w + bv4.w);
  *(ushort4*)(out + (size_t)row*D + t*4) = o;
}

// ---------------------------------------------------------------- head proj v2: MFMA mini-GEMM
// block = 256 thr = 4 waves, one 16-row tile; out[row][head] = X[16,1024] @ Wg^T[1024,16]
// X staged in LDS (glds16, swizzled); W bf16 frags in regs; waves split K 4-way; LDS reduce.
template<bool DUAL>
__global__ __launch_bounds__(256) void headproj2_kernel(const u16* __restrict__ xln,
    const u16* __restrict__ wgb, const float* __restrict__ bg, float* __restrict__ outg,
    const u16* __restrict__ wab, float* __restrict__ outa){
  __shared__ alignas(16) u16 X[16*1024];
  __shared__ f32x4 red[DUAL ? 6 : 3][64];
  int t = threadIdx.x, w = t >> 6, lane = t & 63, g = lane >> 4, l15 = lane & 15;
  int row0 = blockIdx.x*16;
  #pragma unroll
  for(int i = 0; i < 8; ++i){
    int idx = i*256 + t;
    int row = idx >> 7, slot = idx & 127;
    const u16* src = xln + (size_t)(row0 + row)*D + ((slot ^ (row & 7)) << 3);
    glds16(src, &X[idx << 3]);
  }
  bf16x8 wg_[8], wa_[8];
  #pragma unroll
  for(int j = 0; j < 8; ++j){
    int koff = (8*w + j)*32 + g*8;
    wg_[j] = *(const bf16x8*)&wgb[(size_t)l15*D + koff];
    if constexpr (DUAL) wa_[j] = *(const bf16x8*)&wab[(size_t)l15*D + koff];
  }
  asm volatile("s_waitcnt vmcnt(0)");
  __syncthreads();
  f32x4 accg = {}, acca = {};
  #pragma unroll
  for(int j = 0; j < 8; ++j){
    int kk = 8*w + j;
    bf16x8 xa = *(const bf16x8*)&X[l15*1024 + (((kk*4 + g) ^ (l15 & 7)) << 3)];
    accg = __builtin_amdgcn_mfma_f32_16x16x32_bf16(xa, wg_[j], accg, 0, 0, 0);
    if constexpr (DUAL) acca = __builtin_amdgcn_mfma_f32_16x16x32_bf16(xa, wa_[j], acca, 0, 0, 0);
  }
  if(w > 0){
    red[w-1][lane] = accg;
    if constexpr (DUAL) red[w+2][lane] = acca;
  }
  __syncthreads();
  if(w == 0){
    #pragma unroll
    for(int r = 0; r < 3; ++r) accg += red[r][lane];
    if constexpr (DUAL){
      #pragma unroll
      for(int r = 3; r < 6; ++r) acca += red[r][lane];
    }
    float bgv = bg[l15];
    int b = row0 >> 10;
    size_t base = ((size_t)(b*H + l15) << 10) + (row0 & 1023) + g*4;
    #pragma unroll
    for(int i = 0; i < 4; ++i){
      float r = accg[i] + bgv;
      outg[base + i] = 1.f/(1.f + __expf(-r));
      if constexpr (DUAL) outa[base + i] = acca[i];
    }
  }
}

// ---------------------------------------------------------------- GEMM v5 (unchanged from round 5)
template<int MODE, int BM, int BN>
__global__ __launch_bounds__(256) void gemm_t(const u16* __restrict__ A,
    const u16* __restrict__ W0, const u16* __restrict__ W1, const u16* __restrict__ W2,
    const float* __restrict__ b0f, const float* __restrict__ b1f, const float* __restrict__ b2f,
    void* __restrict__ o0, void* __restrict__ o1, void* __restrict__ o2,
    const float* __restrict__ resid){
  constexpr int K = 1024;
  constexpr int RM = BM/32, RN = BN/32;
  constexpr int NBY = 2048/BM;
  constexpr int NBX = ((MODE == 0) ? 3072 : 1024)/BN;
  constexpr int CPX = (NBX*NBY)/8;
  __shared__ alignas(16) u16 As[2*BM*64];
  __shared__ alignas(16) u16 Bs[2*BN*64];
  int bid = blockIdx.x;
  int vid = (bid & 7)*CPX + (bid >> 3);
  int bx = vid / NBY, by = vid % NBY;
  int m0 = by*BM;
  const u16* W; const float* bias; int mat, n0;
  if constexpr (MODE == 0){
    mat = bx >> 3; n0 = (bx & 7)*BN;
    W = (mat == 0) ? W0 : (mat == 1) ? W1 : W2;
    bias = (mat == 0) ? b0f : (mat == 1) ? b1f : b2f;
  } else { mat = 0; n0 = bx*BN; W = W0; bias = b0f; }
  int t = threadIdx.x, w = t >> 6, lane = t & 63, g = lane >> 4, l15 = lane & 15;
  int wr = w >> 1, wc = w & 1;
  int rl = lane >> 3, sl = lane & 7;
  int scol = ((sl ^ rl) << 3);
  f32x4 acc[RM][RN] = {};
  const u16* ag = A + (size_t)(m0 + rl)*K + scol;
  const u16* wg = W + (size_t)(n0 + rl)*K + scol;
  auto STAGE = [&](int kt, int buf){
    #pragma unroll
    for(int j = 0; j < BM/32; ++j){
      int r = w*(BM/4) + j*8;
      glds16(ag + (size_t)r*K + kt*64, &As[buf*BM*64 + r*64]);
    }
    #pragma unroll
    for(int j = 0; j < BN/32; ++j){
      int r = w*(BN/4) + j*8;
      glds16(wg + (size_t)r*K + kt*64, &Bs[buf*BN*64 + r*64]);
    }
  };
  STAGE(0, 0);
  asm volatile("s_waitcnt vmcnt(0)");
  __syncthreads();
  int cur = 0;
  for(int kt = 0; kt < 16; ++kt){
    if(kt + 1 < 16) STAGE(kt + 1, cur ^ 1);
    bf16x8 af[RM][2], bfr[RN][2];
    #pragma unroll
    for(int m = 0; m < RM; ++m)
      #pragma unroll
      for(int ks = 0; ks < 2; ++ks)
        af[m][ks] = *(const bf16x8*)&As[cur*BM*64 + swz(wr*(BM/2) + m*16 + l15, ks*4 + g)];
    #pragma unroll
    for(int n = 0; n < RN; ++n)
      #pragma unroll
      for(int ks = 0; ks < 2; ++ks)
        bfr[n][ks] = *(const bf16x8*)&Bs[cur*BN*64 + swz(wc*(BN/2) + n*16 + l15, ks*4 + g)];
    __builtin_amdgcn_s_setprio(1);
    #pragma unroll
    for(int ks = 0; ks < 2; ++ks)
      #pragma unroll
      for(int m = 0; m < RM; ++m)
        #pragma unroll
        for(int n = 0; n < RN; ++n)
          acc[m][n] = __builtin_amdgcn_mfma_f32_16x16x32_bf16(af[m][ks], bfr[n][ks], acc[m][n], 0, 0, 0);
    __builtin_amdgcn_s_setprio(0);
    if(kt + 1 < 16){
      asm volatile("s_waitcnt vmcnt(0)");
      __syncthreads();
      cur ^= 1;
    }
  }
  #pragma unroll
  for(int m = 0; m < RM; ++m){
    #pragma unroll
    for(int n = 0; n < RN; ++n){
      int ng = n0 + wc*(BN/2) + n*16 + l15;
      float bv = bias ? bias[ng] : 0.f;
      #pragma unroll
      for(int i = 0; i < 4; ++i){
        int mg = m0 + wr*(BM/2) + m*16 + g*4 + i;
        float v = acc[m][n][i] + bv;
        if constexpr (MODE == 0){
          if(mat == 0) v *= 0.125f;
          if(mat < 2){
            u16* o = (mat == 0) ? (u16*)o0 : (u16*)o1;
            o[(size_t)mg*D + ng] = f2bf(v);
          } else {
            int b = mg >> 10, s = mg & 1023;
            ((u16*)o2)[((size_t)(b*D + ng))*S + s] = f2bf(v);
          }
        } else if constexpr (MODE == 1){
          int b = mg >> 10, s = mg & 1023;
          ((u16*)o0)[((size_t)(b*D + ng))*S + s] = f2bf(v);
        } else {
          ((float*)o0)[(size_t)mg*1024 + ng] = resid[(size_t)mg*1024 + ng] + v;
        }
      }
    }
  }
}

// ---------------------------------------------------------------- fused attention v4 (flash-block) — unchanged
__device__ __forceinline__ bf16x8 repack8(const float* s, int g, int l15){
  u32 L0 = pack2(s[0], s[1]), L1 = pack2(s[2], s[3]);
  u32 H0 = pack2(s[4], s[5]), H1 = pack2(s[6], s[7]);
  int base = ((g & 1)*2)*16 + l15;
  u32 a0 = (u32)__shfl((int)L0, base),    a1 = (u32)__shfl((int)L1, base);
  u32 b0 = (u32)__shfl((int)L0, base+16), b1 = (u32)__shfl((int)L1, base+16);
  u32 c0 = (u32)__shfl((int)H0, base),    c1 = (u32)__shfl((int)H1, base);
  u32 d0 = (u32)__shfl((int)H0, base+16), d1 = (u32)__shfl((int)H1, base+16);
  bool hi = g >= 2;
  union { u32 wd[4]; bf16x8 v; } pu;
  pu.wd[0] = hi ? c0 : a0;
  pu.wd[1] = hi ? c1 : a1;
  pu.wd[2] = hi ? d0 : b0;
  pu.wd[3] = hi ? d1 : b1;
  return pu.v;
}

template<int MODE>   // 0: SDPA self; 1: SDPA cross; 2: pool self
__global__ __launch_bounds__(256) void attn4_kernel(const u16* __restrict__ Q,
    const u16* __restrict__ Kb, const u16* __restrict__ Vt,
    const float* __restrict__ aprojT, const int* __restrict__ segd,
    const float* __restrict__ gateT, u16* __restrict__ out){
  constexpr int KSZ = (MODE == 2) ? 16 : 8192;
  __shared__ alignas(16) u16 Klds[KSZ];
  __shared__ alignas(16) u16 Vlds[8192];
  __shared__ int segL[1024];
  __shared__ float apL[(MODE == 2) ? 1024 : 16];
  __shared__ u16 ot[4][16][72];
  int bid = blockIdx.x;
  int vid = (bid & 7)*64 + (bid >> 3);
  int bh = vid >> 4, qb = 15 - (vid & 15);
  int b = bh >> 4, h = bh & 15;
  int t = threadIdx.x, w = t >> 6, lane = t & 63, g = lane >> 4, l15 = lane & 15;
  { int4 v = ((const int4*)(segd + b*S))[t]; *(int4*)&segL[t*4] = v; }
  if constexpr (MODE == 2){
    float4 v = ((const float4*)(aprojT + ((size_t)bh << 10)))[t];
    *(float4*)&apL[t*4] = v;
  }
  int qt = qb*4 + w, q = qt*16 + l15;
  float hs = exp2f(-(float)(h + 1) * 0.5f);
  int rl = lane >> 3, sl = lane & 7;
  int scol = ((sl ^ rl) << 3);
  bf16x8 qf0 = {}, qf1 = {};
  if constexpr (MODE != 2){
    const u16* qp = Q + ((size_t)(b*S + q))*D + h*DK + g*8;
    qf0 = *(const bf16x8*)qp;
    qf1 = *(const bf16x8*)(qp + 32);
  }
  auto STAGE = [&](int buf, int kc){
    int k0 = kc*64;
    if constexpr (MODE != 2){
      const u16* kg = Kb + (size_t)(b*S + k0 + w*16 + rl)*D + h*DK + scol;
      glds16(kg,               &Klds[buf*4096 + w*1024]);
      glds16(kg + (size_t)8*D, &Klds[buf*4096 + w*1024 + 512]);
    }
    const u16* vg = Vt + (size_t)(bh*DK + w*16 + rl)*S + k0 + scol;
    glds16(vg,               &Vlds[buf*4096 + w*1024]);
    glds16(vg + (size_t)8*S, &Vlds[buf*4096 + w*1024 + 512]);
  };

  f32x4 oacc[4] = {};
  float mrun = NEGF, lsum = 0.f;
  int sdq = 0, seg_q = 0, mq = 0;

  int nc = qb + 1;
  STAGE(0, 0);
  asm volatile("s_waitcnt vmcnt(0)");
  __syncthreads();
  sdq = segL[q]; seg_q = sdq >> 2; mq = sdq & 1;

  int cur = 0;
  for(int kc = 0; kc < nc; ++kc){
    if(kc + 1 < nc) STAGE(cur ^ 1, kc + 1);
    int k0 = kc*64;
    const u16* KL = &Klds[cur*4096];
    const u16* VL = &Vlds[cur*4096];
    bf16x8 vr[2][4];
    #pragma unroll
    for(int ks = 0; ks < 2; ++ks)
      #pragma unroll
      for(int c = 0; c < 4; ++c)
        vr[ks][c] = *(const bf16x8*)&VL[swz(c*16 + l15, ks*4 + g)];
    float sv[16];
    if constexpr (MODE != 2){
      __builtin_amdgcn_s_setprio(1);
      #pragma unroll
      for(int r = 0; r < 4; ++r){
        f32x4 sa = {};
        sa = __builtin_amdgcn_mfma_f32_16x16x32_bf16(
               *(const bf16x8*)&KL[swz(r*16 + l15, g)],     qf0, sa, 0, 0, 0);
        sa = __builtin_amdgcn_mfma_f32_16x16x32_bf16(
               *(const bf16x8*)&KL[swz(r*16 + l15, 4 + g)], qf1, sa, 0, 0, 0);
        #pragma unroll
        for(int i = 0; i < 4; ++i) sv[r*4+i] = sa[i];
      }
      __builtin_amdgcn_s_setprio(0);
    } else {
      #pragma unroll
      for(int r = 0; r < 4; ++r){
        float4 a4 = *(const float4*)&apL[k0 + r*16 + g*4];
        sv[r*4+0] = a4.x; sv[r*4+1] = a4.y; sv[r*4+2] = a4.z; sv[r*4+3] = a4.w;
      }
    }
    #pragma unroll
    for(int r = 0; r < 4; ++r){
      int4 sd4 = *(const int4*)&segL[k0 + r*16 + g*4];
      int sds[4] = { sd4.x, sd4.y, sd4.z, sd4.w };
      #pragma unroll
      for(int i = 0; i < 4; ++i){
        int key = k0 + r*16 + g*4 + i;
        int sdk = sds[i];
        bool ok; float val;
        if constexpr (MODE == 1){
          ok = (key < q && (sdk & 2)) || (key == q);
          val = (float)((sdk >> 2) - seg_q);
        } else {
          ok = (key < q && ((sdk >> 2) == seg_q) && (sdk & mq & 1)) || (key == q);
          val = (float)(key - q);
        }
        sv[r*4+i] = ok ? sv[r*4+i] + val*hs : NEGF;
      }
    }
    float cm = sv[0];
    #pragma unroll
    for(int i = 1; i < 16; ++i) cm = fmaxf(cm, sv[i]);
    cm = fmaxf(cm, __shfl_xor(cm, 16));
    cm = fmaxf(cm, __shfl_xor(cm, 32));
    float mnew = fmaxf(mrun, cm);
    float fac = __expf(mrun - mnew);
    float ps = 0.f;
    #pragma unroll
    for(int i = 0; i < 16; ++i){ sv[i] = __expf(sv[i] - mnew); ps += sv[i]; }
    ps += __shfl_xor(ps, 16);
    ps += __shfl_xor(ps, 32);
    lsum = lsum * fac + ps;
    mrun = mnew;
    #pragma unroll
    for(int c = 0; c < 4; ++c)
      #pragma unroll
      for(int i = 0; i < 4; ++i) oacc[c][i] *= fac;
    __builtin_amdgcn_s_setprio(1);
    #pragma unroll
    for(int ks = 0; ks < 2; ++ks){
      bf16x8 pf = repack8(&sv[ks*8], g, l15);
      #pragma unroll
      for(int c = 0; c < 4; ++c)
        oacc[c] = __builtin_amdgcn_mfma_f32_16x16x32_bf16(vr[ks][c], pf, oacc[c], 0, 0, 0);
    }
    __builtin_amdgcn_s_setprio(0);
    if(kc + 1 < nc){
      asm volatile("s_waitcnt vmcnt(0)");
      __syncthreads();
      cur ^= 1;
    }
  }

  float scale = (1.f / lsum) * gateT[((size_t)bh << 10) + q];
  #pragma unroll
  for(int c = 0; c < 4; ++c)
    #pragma unroll
    for(int i = 0; i < 4; i += 2){
      u32 p = pack2(oacc[c][i]*scale, oacc[c][i+1]*scale);
      *(u32*)&ot[w][l15][c*16 + g*4 + i] = p;
    }
  int r = lane >> 2, c4 = lane & 3;
  uint4 v0 = *(uint4*)&ot[w][r][c4*16];
  uint4 v1 = *(uint4*)&ot[w][r][c4*16 + 8];
  u16* op = out + ((size_t)(b*S + qt*16 + r))*D + h*DK + c4*16;
  *(uint4*)op = v0;
  *(uint4*)(op + 8) = v1;
}

} // namespace

extern "C" void kernel_launch(void* const* d_in, const int* in_sizes, int n_in,
                              void* d_out, int out_size, void* d_ws, size_t ws_size,
                              hipStream_t stream){
  (void)in_sizes; (void)n_in; (void)out_size; (void)ws_size;
  const float* states = (const float*)d_in[0];
  const int*   ids    = (const int*)d_in[1];
  float* xout = (float*)d_out;

  char* w = (char*)d_ws;
  u16* wbf[10];
  for(int i = 0; i < 10; ++i){ wbf[i] = (u16*)w; w += (size_t)1024*1024*2; }
  u16* wsm[4];
  for(int i = 0; i < 4; ++i){ wsm[i] = (u16*)w; w += (size_t)16*1024*2; }
  u16* xln  = (u16*)w; w += (size_t)2048*1024*2;
  u16* qb   = (u16*)w; w += (size_t)2048*1024*2;
  u16* kb   = (u16*)w; w += (size_t)2048*1024*2;
  u16* vt   = (u16*)w; w += (size_t)2048*1024*2;
  u16* attn = (u16*)w; w += (size_t)2048*1024*2;
  float* gateT  = (float*)w; w += (size_t)2048*16*4;
  float* aprojT = (float*)w; w += (size_t)2048*16*4;
  int* segd = (int*)w;

  // big weights: l0 qw4 kw6 vw8 ow12 | l1 vw17 ow21 | l2 qw25 kw27 vw29 ow33
  const int widx[10] = {4, 6, 8, 12, 17, 21, 25, 27, 29, 33};
  CvtArgs ca;
  for(int i = 0; i < 10; ++i){ ca.src[i] = (const float*)d_in[widx[i]]; ca.dst[i] = wbf[i]; }
  cvt_kernel<<<dim3(512, 10), dim3(256), 0, stream>>>(ca);
  // small head mats: l0 gw10, l1 gw19, l2 gw31, l1 aw16
  const int sidx[4] = {10, 19, 31, 16};
  CvtArgs cs = {};
  for(int i = 0; i < 4; ++i){ cs.src[i] = (const float*)d_in[sidx[i]]; cs.dst[i] = wsm[i]; }
  cvt_kernel<<<dim3(8, 4), dim3(256), 0, stream>>>(cs);
  seg_kernel<<<dim3(2), dim3(1024), 0, stream>>>(ids, segd);

  dim3 b256(256), g2048(2048);
  dim3 gqkv(384), ggen(256), gattn(512), ghp(128);

  // ---- layer 0: SDPA, self bias
  ln_kernel<<<g2048, b256, 0, stream>>>(states, (const float*)d_in[2], (const float*)d_in[3], xln);
  gemm_t<0,128,128><<<gqkv, b256, 0, stream>>>(xln, wbf[0], wbf[1], wbf[2],
      (const float*)d_in[5], (const float*)d_in[7], (const float*)d_in[9], qb, kb, vt, nullptr);
  headproj2_kernel<false><<<ghp, b256, 0, stream>>>(xln, wsm[0], (const float*)d_in[11], gateT, nullptr, nullptr);
  attn4_kernel<0><<<gattn, b256, 0, stream>>>(qb, kb, vt, nullptr, segd, gateT, attn);
  gemm_t<2,128,64><<<ggen, b256, 0, stream>>>(attn, wbf[3], nullptr, nullptr,
      (const float*)d_in[13], nullptr, nullptr, xout, nullptr, nullptr, states);

  // ---- layer 1: pool, self bias
  ln_kernel<<<g2048, b256, 0, stream>>>(xout, (const float*)d_in[14], (const float*)d_in[15], xln);
  gemm_t<1,128,64><<<ggen, b256, 0, stream>>>(xln, wbf[4], nullptr, nullptr,
      (const float*)d_in[18], nullptr, nullptr, vt, nullptr, nullptr, nullptr);
  headproj2_kernel<true><<<ghp, b256, 0, stream>>>(xln, wsm[1], (const float*)d_in[20], gateT, wsm[3], aprojT);
  attn4_kernel<2><<<gattn, b256, 0, stream>>>(nullptr, nullptr, vt, aprojT, segd, gateT, attn);
  gemm_t<2,128,64><<<ggen, b256, 0, stream>>>(attn, wbf[5], nullptr, nullptr,
      (const float*)d_in[22], nullptr, nullptr, xout, nullptr, nullptr, xout);

  // ---- layer 2: SDPA, cross bias
  ln_kernel<<<g2048, b256, 0, stream>>>(xout, (const float*)d_in[23], (const float*)d_in[24], xln);
  gemm_t<0,128,128><<<gqkv, b256, 0, stream>>>(xln, wbf[6], wbf[7], wbf[8],
      (const float*)d_in[26], (const float*)d_in[28], (const float*)d_in[30], qb, kb, vt, nullptr);
  headproj2_kernel<false><<<ghp, b256, 0, stream>>>(xln, wsm[2], (const float*)d_in[32], gateT, nullptr, nullptr);
  attn4_kernel<1><<<gattn, b256, 0, stream>>>(qb, kb, vt, nullptr, segd, gateT, attn);
  gemm_t<2,128,64><<<ggen, b256, 0, stream>>>(attn, wbf[9], nullptr, nullptr,
      (const float*)d_in[34], nullptr, nullptr, xout, nullptr, nullptr, xout);
}

// Round 8
// 368.181 us; speedup vs baseline: 1.5124x; 1.1420x over previous
//
#include <hip/hip_runtime.h>

typedef unsigned short u16;
typedef unsigned int u32;
typedef __attribute__((ext_vector_type(8))) short bf16x8;
typedef __attribute__((ext_vector_type(4))) float f32x4;

namespace {

constexpr int S = 1024, D = 1024, H = 16, DK = 64;
constexpr float NEGF = -1e30f;

__device__ __forceinline__ u16 f2bf(float f){
  u32 u = __builtin_bit_cast(u32, f);
  u32 r = (u + 0x7fffu + ((u >> 16) & 1u)) >> 16;
  return (u16)r;
}
__device__ __forceinline__ float bf2f(u16 h){
  u32 u = ((u32)h) << 16;
  return __builtin_bit_cast(float, u);
}
__device__ __forceinline__ u32 pack2(float a, float b){
  return (u32)f2bf(a) | ((u32)f2bf(b) << 16);
}
__device__ __forceinline__ void glds16(const u16* g, u16* l){
  __builtin_amdgcn_global_load_lds(
      (const __attribute__((address_space(1))) u32*)g,
      (__attribute__((address_space(3))) u32*)l, 16, 0, 0);
}
// XOR-swizzled LDS address (u16 units). Rows are 64 elems (128B), slot = 16B chunk.
__device__ __forceinline__ int swz(int row, int slot){
  return row*64 + ((slot ^ (row & 7)) << 3);
}

// ---------------------------------------------------------------- ln body (shared by prologue & ln_kernel)
__device__ __forceinline__ void ln_body(const float* __restrict__ x,
    const float* __restrict__ w, const float* __restrict__ bias, u16* __restrict__ out,
    int row, int t, float* ls, float* lq){
  float4 v = ((const float4*)(x + (size_t)row*D))[t];
  float s = v.x + v.y + v.z + v.w;
  float q = v.x*v.x + v.y*v.y + v.z*v.z + v.w*v.w;
  for(int off = 32; off >= 1; off >>= 1){ s += __shfl_down(s, off); q += __shfl_down(q, off); }
  int wv = t >> 6, ln = t & 63;
  if(ln == 0){ ls[wv] = s; lq[wv] = q; }
  __syncthreads();
  s = ls[0] + ls[1] + ls[2] + ls[3];
  q = lq[0] + lq[1] + lq[2] + lq[3];
  float mean = s * (1.f/D);
  float var  = q * (1.f/D) - mean*mean;
  float rs = rsqrtf(var + 1e-5f);
  float4 wv4 = ((const float4*)w)[t];
  float4 bv4 = ((const float4*)bias)[t];
  ushort4 o;
  o.x = f2bf((v.x-mean)*rs*wv4.x + bv4.x);
  o.y = f2bf((v.y-mean)*rs*wv4.y + bv4.y);
  o.z = f2bf((v.z-mean)*rs*wv4.z + bv4.z);
  o.w = f2bf((v.w-mean)*rs*wv4.w + bv4.w);
  *(ushort4*)(out + (size_t)row*D + t*4) = o;
}

__global__ __launch_bounds__(256) void ln_kernel(const float* __restrict__ x,
    const float* __restrict__ w, const float* __restrict__ bias, u16* __restrict__ out){
  __shared__ float ls[4], lq[4];
  ln_body(x, w, bias, out, blockIdx.x, threadIdx.x, ls, lq);
}

// ---------------------------------------------------------------- prologue: cvt(5152) + seg(2) + ln0(2048)
struct CvtArgs { const float* src[14]; u16* dst[14]; };
__global__ __launch_bounds__(256) void prologue_kernel(CvtArgs ca,
    const int* __restrict__ ids, int* __restrict__ segd,
    const float* __restrict__ x, const float* __restrict__ lnw,
    const float* __restrict__ lnb, u16* __restrict__ xln){
  __shared__ int ws_[256];
  __shared__ float ls[4], lq[4];
  int bid = blockIdx.x, t = threadIdx.x;
  if(bid < 5120){
    int m = bid >> 9;
    const float* s = ca.src[m]; u16* d = ca.dst[m];
    int i = (((bid & 511)*256) + t)*8;
    float4 v0 = *(const float4*)(s + i), v1 = *(const float4*)(s + i + 4);
    u32 p[4] = { pack2(v0.x,v0.y), pack2(v0.z,v0.w), pack2(v1.x,v1.y), pack2(v1.z,v1.w) };
    *(uint4*)(d + i) = *(uint4*)p;
  } else if(bid < 5152){
    int idx = bid - 5120;
    int m = 10 + (idx >> 3);
    const float* s = ca.src[m]; u16* d = ca.dst[m];
    int i = (((idx & 7)*256) + t)*8;
    float4 v0 = *(const float4*)(s + i), v1 = *(const float4*)(s + i + 4);
    u32 p[4] = { pack2(v0.x,v0.y), pack2(v0.z,v0.w), pack2(v1.x,v1.y), pack2(v1.z,v1.w) };
    *(uint4*)(d + i) = *(uint4*)p;
  } else if(bid < 5154){
    int b = bid - 5152;
    int4 id4 = ((const int4*)(ids + b*S))[t];
    int c0 = (id4.x == 1);
    int c1 = c0 + (id4.y == 1);
    int c2 = c1 + (id4.z == 1);
    int c3 = c2 + (id4.w == 1);
    ws_[t] = c3;
    __syncthreads();
    for(int off = 1; off < 256; off <<= 1){
      int a = (t >= off) ? ws_[t - off] : 0;
      __syncthreads();
      ws_[t] += a;
      __syncthreads();
    }
    int ex = (t > 0) ? ws_[t-1] : 0;
    int4 o;
    o.x = ((ex+c0) << 2) | ((id4.x == 2) ? 2 : 0) | ((id4.x != 0) ? 1 : 0);
    o.y = ((ex+c1) << 2) | ((id4.y == 2) ? 2 : 0) | ((id4.y != 0) ? 1 : 0);
    o.z = ((ex+c2) << 2) | ((id4.z == 2) ? 2 : 0) | ((id4.z != 0) ? 1 : 0);
    o.w = ((ex+c3) << 2) | ((id4.w == 2) ? 2 : 0) | ((id4.w != 0) ? 1 : 0);
    ((int4*)(segd + b*S))[t] = o;
  } else {
    ln_body(x, lnw, lnb, xln, bid - 5154, t, ls, lq);
  }
}

// ---------------------------------------------------------------- head proj body (MFMA mini-GEMM)
template<bool DUAL>
__device__ __forceinline__ void headproj_body(u16* sm, int bid, const u16* __restrict__ xln,
    const u16* __restrict__ wgb, const float* __restrict__ bg, float* __restrict__ outg,
    const u16* __restrict__ wab, float* __restrict__ outa){
  u16* X = sm;                         // 16*1024 u16 = 32KB
  f32x4* red = (f32x4*)(sm + 16384);   // up to 6*64 f32x4 = 6KB
  int t = threadIdx.x, w = t >> 6, lane = t & 63, g = lane >> 4, l15 = lane & 15;
  int row0 = bid*16;
  #pragma unroll
  for(int i = 0; i < 8; ++i){
    int idx = i*256 + t;
    int row = idx >> 7, slot = idx & 127;
    const u16* src = xln + (size_t)(row0 + row)*D + ((slot ^ (row & 7)) << 3);
    glds16(src, &X[idx << 3]);
  }
  bf16x8 wg_[8], wa_[8];
  #pragma unroll
  for(int j = 0; j < 8; ++j){
    int koff = (8*w + j)*32 + g*8;
    wg_[j] = *(const bf16x8*)&wgb[(size_t)l15*D + koff];
    if constexpr (DUAL) wa_[j] = *(const bf16x8*)&wab[(size_t)l15*D + koff];
  }
  asm volatile("s_waitcnt vmcnt(0)");
  __syncthreads();
  f32x4 accg = {}, acca = {};
  #pragma unroll
  for(int j = 0; j < 8; ++j){
    int kk = 8*w + j;
    bf16x8 xa = *(const bf16x8*)&X[l15*1024 + (((kk*4 + g) ^ (l15 & 7)) << 3)];
    accg = __builtin_amdgcn_mfma_f32_16x16x32_bf16(xa, wg_[j], accg, 0, 0, 0);
    if constexpr (DUAL) acca = __builtin_amdgcn_mfma_f32_16x16x32_bf16(xa, wa_[j], acca, 0, 0, 0);
  }
  if(w > 0){
    red[(w-1)*64 + lane] = accg;
    if constexpr (DUAL) red[(w+2)*64 + lane] = acca;
  }
  __syncthreads();
  if(w == 0){
    #pragma unroll
    for(int r = 0; r < 3; ++r) accg += red[r*64 + lane];
    if constexpr (DUAL){
      #pragma unroll
      for(int r = 3; r < 6; ++r) acca += red[r*64 + lane];
    }
    float bgv = bg[l15];
    int b = row0 >> 10;
    size_t base = ((size_t)(b*H + l15) << 10) + (row0 & 1023) + g*4;
    #pragma unroll
    for(int i = 0; i < 4; ++i){
      float r = accg[i] + bgv;
      outg[base + i] = 1.f/(1.f + __expf(-r));
      if constexpr (DUAL) outa[base + i] = acca[i];
    }
  }
}

// ---------------------------------------------------------------- GEMM body: bf16 operands, glds16, BK=64,
// swizzled LDS, 2-phase dbuf. MODE 0: fused qkv (BN=128; q scaled 0.125; v -> LDS-transposed vt out)
// MODE 1: LDS-transposed vt out;  MODE 2: f32 + resid
template<int MODE, int BM, int BN>
__device__ __forceinline__ void gemm_body(u16* sm, int vid,
    const u16* __restrict__ A, const u16* __restrict__ W0, const u16* __restrict__ W1,
    const u16* __restrict__ W2, const float* __restrict__ b0f, const float* __restrict__ b1f,
    const float* __restrict__ b2f, void* __restrict__ o0, void* __restrict__ o1,
    void* __restrict__ o2, const float* __restrict__ resid){
  constexpr int K = 1024;
  constexpr int RM = BM/32, RN = BN/32;
  constexpr int NBY = 2048/BM;
  u16* As = sm;
  u16* Bs = sm + 2*BM*64;
  int bx = vid / NBY, by = vid % NBY;
  int m0 = by*BM;
  const u16* W; const float* bias; int mat, n0;
  if constexpr (MODE == 0){
    mat = bx >> 3; n0 = (bx & 7)*BN;
    W = (mat == 0) ? W0 : (mat == 1) ? W1 : W2;
    bias = (mat == 0) ? b0f : (mat == 1) ? b1f : b2f;
  } else { mat = 0; n0 = bx*BN; W = W0; bias = b0f; }
  int t = threadIdx.x, w = t >> 6, lane = t & 63, g = lane >> 4, l15 = lane & 15;
  int wr = w >> 1, wc = w & 1;
  int rl = lane >> 3, sl = lane & 7;
  int scol = ((sl ^ rl) << 3);
  f32x4 acc[RM][RN] = {};
  const u16* ag = A + (size_t)(m0 + rl)*K + scol;
  const u16* wg = W + (size_t)(n0 + rl)*K + scol;
  auto STAGE = [&](int kt, int buf){
    #pragma unroll
    for(int j = 0; j < BM/32; ++j){
      int r = w*(BM/4) + j*8;
      glds16(ag + (size_t)r*K + kt*64, &As[buf*BM*64 + r*64]);
    }
    #pragma unroll
    for(int j = 0; j < BN/32; ++j){
      int r = w*(BN/4) + j*8;
      glds16(wg + (size_t)r*K + kt*64, &Bs[buf*BN*64 + r*64]);
    }
  };
  STAGE(0, 0);
  asm volatile("s_waitcnt vmcnt(0)");
  __syncthreads();
  int cur = 0;
  for(int kt = 0; kt < 16; ++kt){
    if(kt + 1 < 16) STAGE(kt + 1, cur ^ 1);
    bf16x8 af[RM][2], bfr[RN][2];
    #pragma unroll
    for(int m = 0; m < RM; ++m)
      #pragma unroll
      for(int ks = 0; ks < 2; ++ks)
        af[m][ks] = *(const bf16x8*)&As[cur*BM*64 + swz(wr*(BM/2) + m*16 + l15, ks*4 + g)];
    #pragma unroll
    for(int n = 0; n < RN; ++n)
      #pragma unroll
      for(int ks = 0; ks < 2; ++ks)
        bfr[n][ks] = *(const bf16x8*)&Bs[cur*BN*64 + swz(wc*(BN/2) + n*16 + l15, ks*4 + g)];
    __builtin_amdgcn_s_setprio(1);
    #pragma unroll
    for(int ks = 0; ks < 2; ++ks)
      #pragma unroll
      for(int m = 0; m < RM; ++m)
        #pragma unroll
        for(int n = 0; n < RN; ++n)
          acc[m][n] = __builtin_amdgcn_mfma_f32_16x16x32_bf16(af[m][ks], bfr[n][ks], acc[m][n], 0, 0, 0);
    __builtin_amdgcn_s_setprio(0);
    if(kt + 1 < 16){
      asm volatile("s_waitcnt vmcnt(0)");
      __syncthreads();
      cur ^= 1;
    }
  }
  // ---------------- epilogue
  bool transpose = (MODE == 1) || (MODE == 0 && mat == 2);
  if(!transpose){
    #pragma unroll
    for(int m = 0; m < RM; ++m){
      #pragma unroll
      for(int n = 0; n < RN; ++n){
        int ng = n0 + wc*(BN/2) + n*16 + l15;
        float bv = bias ? bias[ng] : 0.f;
        #pragma unroll
        for(int i = 0; i < 4; ++i){
          int mg = m0 + wr*(BM/2) + m*16 + g*4 + i;
          float v = acc[m][n][i] + bv;
          if constexpr (MODE == 0){
            if(mat == 0) v *= 0.125f;
            u16* o = (mat == 0) ? (u16*)o0 : (u16*)o1;
            o[(size_t)mg*D + ng] = f2bf(v);
          } else if constexpr (MODE == 2){
            ((float*)o0)[(size_t)mg*1024 + ng] = resid[(size_t)mg*1024 + ng] + v;
          }
        }
      }
    }
  } else {
    // LDS-staged transpose -> coalesced 16B stores to [b, d, s]
    __syncthreads();                   // all ds_reads of K-loop done; reuse sm
    u16* tile = sm;                    // [BN][BM] padded rows of 136
    #pragma unroll
    for(int m = 0; m < RM; ++m){
      #pragma unroll
      for(int n = 0; n < RN; ++n){
        int ngl = wc*(BN/2) + n*16 + l15;
        float bv = bias[n0 + ngl];
        #pragma unroll
        for(int i = 0; i < 4; i += 2){
          int mgl = wr*(BM/2) + m*16 + g*4 + i;
          u32 p = pack2(acc[m][n][i] + bv, acc[m][n][i+1] + bv);
          *(u32*)&tile[ngl*136 + mgl] = p;
        }
      }
    }
    __syncthreads();
    int bq = m0 >> 10, m0s = m0 & 1023;
    constexpr int TPR = 256/BN;        // threads per tile row
    constexpr int CW  = BM/TPR;        // cols per thread
    int ng = t / TPR, mgc = (t % TPR)*CW;
    void* ovt = (MODE == 0) ? o2 : o0;
    u16* dst = (u16*)ovt + ((size_t)(bq*D + n0 + ng))*S + m0s + mgc;
    const u16* srcp = &tile[ng*136 + mgc];
    #pragma unroll
    for(int j = 0; j < CW/8; ++j)
      *(uint4*)(dst + j*8) = *(const uint4*)(srcp + j*8);
  }
}

// ---------------------------------------------------------------- fused projection kernels
__global__ __launch_bounds__(256) void proj_sdpa_kernel(const u16* __restrict__ xln,
    const u16* __restrict__ Wq, const u16* __restrict__ Wk, const u16* __restrict__ Wv,
    const float* __restrict__ bq_, const float* __restrict__ bk_, const float* __restrict__ bv_,
    u16* __restrict__ oq, u16* __restrict__ ok, u16* __restrict__ ovt,
    const u16* __restrict__ wgb, const float* __restrict__ bg, float* __restrict__ gateT){
  __shared__ alignas(16) u16 sm[32768];    // 64KB
  int bid = blockIdx.x;
  if(bid < 128){
    headproj_body<false>(sm, bid, xln, wgb, bg, gateT, nullptr, nullptr);
  } else {
    int q = bid - 128;
    int vid = (q & 7)*48 + (q >> 3);       // 384 blocks, XCD-chunked
    gemm_body<0,128,128>(sm, vid, xln, Wq, Wk, Wv, bq_, bk_, bv_, oq, ok, ovt, nullptr);
  }
}

__global__ __launch_bounds__(256) void proj_pool_kernel(const u16* __restrict__ xln,
    const u16* __restrict__ Wv, const float* __restrict__ bv_, u16* __restrict__ ovt,
    const u16* __restrict__ wgb, const float* __restrict__ bg, float* __restrict__ gateT,
    const u16* __restrict__ wab, float* __restrict__ aprojT){
  __shared__ alignas(16) u16 sm[24576];    // 48KB
  int bid = blockIdx.x;
  if(bid < 128){
    headproj_body<true>(sm, bid, xln, wgb, bg, gateT, wab, aprojT);
  } else {
    int q = bid - 128;
    int vid = (q & 7)*32 + (q >> 3);       // 256 blocks
    gemm_body<1,128,64>(sm, vid, xln, Wv, nullptr, nullptr, bv_, nullptr, nullptr,
                        ovt, nullptr, nullptr, nullptr);
  }
}

__global__ __launch_bounds__(256) void oproj_kernel(const u16* __restrict__ attn,
    const u16* __restrict__ W, const float* __restrict__ bias,
    float* __restrict__ xout, const float* __restrict__ resid){
  __shared__ alignas(16) u16 sm[24576];
  int bid = blockIdx.x;
  int vid = (bid & 7)*32 + (bid >> 3);
  gemm_body<2,128,64>(sm, vid, attn, W, nullptr, nullptr, bias, nullptr, nullptr,
                      xout, nullptr, nullptr, resid);
}

// ---------------------------------------------------------------- fused attention v4 (flash-block) — unchanged
__device__ __forceinline__ bf16x8 repack8(const float* s, int g, int l15){
  u32 L0 = pack2(s[0], s[1]), L1 = pack2(s[2], s[3]);
  u32 H0 = pack2(s[4], s[5]), H1 = pack2(s[6], s[7]);
  int base = ((g & 1)*2)*16 + l15;
  u32 a0 = (u32)__shfl((int)L0, base),    a1 = (u32)__shfl((int)L1, base);
  u32 b0 = (u32)__shfl((int)L0, base+16), b1 = (u32)__shfl((int)L1, base+16);
  u32 c0 = (u32)__shfl((int)H0, base),    c1 = (u32)__shfl((int)H1, base);
  u32 d0 = (u32)__shfl((int)H0, base+16), d1 = (u32)__shfl((int)H1, base+16);
  bool hi = g >= 2;
  union { u32 wd[4]; bf16x8 v; } pu;
  pu.wd[0] = hi ? c0 : a0;
  pu.wd[1] = hi ? c1 : a1;
  pu.wd[2] = hi ? d0 : b0;
  pu.wd[3] = hi ? d1 : b1;
  return pu.v;
}

template<int MODE>   // 0: SDPA self; 1: SDPA cross; 2: pool self
__global__ __launch_bounds__(256) void attn4_kernel(const u16* __restrict__ Q,
    const u16* __restrict__ Kb, const u16* __restrict__ Vt,
    const float* __restrict__ aprojT, const int* __restrict__ segd,
    const float* __restrict__ gateT, u16* __restrict__ out){
  constexpr int KSZ = (MODE == 2) ? 16 : 8192;
  __shared__ alignas(16) u16 Klds[KSZ];
  __shared__ alignas(16) u16 Vlds[8192];
  __shared__ int segL[1024];
  __shared__ float apL[(MODE == 2) ? 1024 : 16];
  __shared__ u16 ot[4][16][72];
  int bid = blockIdx.x;
  int vid = (bid & 7)*64 + (bid >> 3);
  int bh = vid >> 4, qb = 15 - (vid & 15);
  int b = bh >> 4, h = bh & 15;
  int t = threadIdx.x, w = t >> 6, lane = t & 63, g = lane >> 4, l15 = lane & 15;
  { int4 v = ((const int4*)(segd + b*S))[t]; *(int4*)&segL[t*4] = v; }
  if constexpr (MODE == 2){
    float4 v = ((const float4*)(aprojT + ((size_t)bh << 10)))[t];
    *(float4*)&apL[t*4] = v;
  }
  int qt = qb*4 + w, q = qt*16 + l15;
  float hs = exp2f(-(float)(h + 1) * 0.5f);
  int rl = lane >> 3, sl = lane & 7;
  int scol = ((sl ^ rl) << 3);
  bf16x8 qf0 = {}, qf1 = {};
  if constexpr (MODE != 2){
    const u16* qp = Q + ((size_t)(b*S + q))*D + h*DK + g*8;
    qf0 = *(const bf16x8*)qp;
    qf1 = *(const bf16x8*)(qp + 32);
  }
  auto STAGE = [&](int buf, int kc){
    int k0 = kc*64;
    if constexpr (MODE != 2){
      const u16* kg = Kb + (size_t)(b*S + k0 + w*16 + rl)*D + h*DK + scol;
      glds16(kg,               &Klds[buf*4096 + w*1024]);
      glds16(kg + (size_t)8*D, &Klds[buf*4096 + w*1024 + 512]);
    }
    const u16* vg = Vt + (size_t)(bh*DK + w*16 + rl)*S + k0 + scol;
    glds16(vg,               &Vlds[buf*4096 + w*1024]);
    glds16(vg + (size_t)8*S, &Vlds[buf*4096 + w*1024 + 512]);
  };

  f32x4 oacc[4] = {};
  float mrun = NEGF, lsum = 0.f;
  int sdq = 0, seg_q = 0, mq = 0;

  int nc = qb + 1;
  STAGE(0, 0);
  asm volatile("s_waitcnt vmcnt(0)");
  __syncthreads();
  sdq = segL[q]; seg_q = sdq >> 2; mq = sdq & 1;

  int cur = 0;
  for(int kc = 0; kc < nc; ++kc){
    if(kc + 1 < nc) STAGE(cur ^ 1, kc + 1);
    int k0 = kc*64;
    const u16* KL = &Klds[cur*4096];
    const u16* VL = &Vlds[cur*4096];
    bf16x8 vr[2][4];
    #pragma unroll
    for(int ks = 0; ks < 2; ++ks)
      #pragma unroll
      for(int c = 0; c < 4; ++c)
        vr[ks][c] = *(const bf16x8*)&VL[swz(c*16 + l15, ks*4 + g)];
    float sv[16];
    if constexpr (MODE != 2){
      __builtin_amdgcn_s_setprio(1);
      #pragma unroll
      for(int r = 0; r < 4; ++r){
        f32x4 sa = {};
        sa = __builtin_amdgcn_mfma_f32_16x16x32_bf16(
               *(const bf16x8*)&KL[swz(r*16 + l15, g)],     qf0, sa, 0, 0, 0);
        sa = __builtin_amdgcn_mfma_f32_16x16x32_bf16(
               *(const bf16x8*)&KL[swz(r*16 + l15, 4 + g)], qf1, sa, 0, 0, 0);
        #pragma unroll
        for(int i = 0; i < 4; ++i) sv[r*4+i] = sa[i];
      }
      __builtin_amdgcn_s_setprio(0);
    } else {
      #pragma unroll
      for(int r = 0; r < 4; ++r){
        float4 a4 = *(const float4*)&apL[k0 + r*16 + g*4];
        sv[r*4+0] = a4.x; sv[r*4+1] = a4.y; sv[r*4+2] = a4.z; sv[r*4+3] = a4.w;
      }
    }
    #pragma unroll
    for(int r = 0; r < 4; ++r){
      int4 sd4 = *(const int4*)&segL[k0 + r*16 + g*4];
      int sds[4] = { sd4.x, sd4.y, sd4.z, sd4.w };
      #pragma unroll
      for(int i = 0; i < 4; ++i){
        int key = k0 + r*16 + g*4 + i;
        int sdk = sds[i];
        bool ok; float val;
        if constexpr (MODE == 1){
          ok = (key < q && (sdk & 2)) || (key == q);
          val = (float)((sdk >> 2) - seg_q);
        } else {
          ok = (key < q && ((sdk >> 2) == seg_q) && (sdk & mq & 1)) || (key == q);
          val = (float)(key - q);
        }
        sv[r*4+i] = ok ? sv[r*4+i] + val*hs : NEGF;
      }
    }
    float cm = sv[0];
    #pragma unroll
    for(int i = 1; i < 16; ++i) cm = fmaxf(cm, sv[i]);
    cm = fmaxf(cm, __shfl_xor(cm, 16));
    cm = fmaxf(cm, __shfl_xor(cm, 32));
    float mnew = fmaxf(mrun, cm);
    float fac = __expf(mrun - mnew);
    float ps = 0.f;
    #pragma unroll
    for(int i = 0; i < 16; ++i){ sv[i] = __expf(sv[i] - mnew); ps += sv[i]; }
    ps += __shfl_xor(ps, 16);
    ps += __shfl_xor(ps, 32);
    lsum = lsum * fac + ps;
    mrun = mnew;
    #pragma unroll
    for(int c = 0; c < 4; ++c)
      #pragma unroll
      for(int i = 0; i < 4; ++i) oacc[c][i] *= fac;
    __builtin_amdgcn_s_setprio(1);
    #pragma unroll
    for(int ks = 0; ks < 2; ++ks){
      bf16x8 pf = repack8(&sv[ks*8], g, l15);
      #pragma unroll
      for(int c = 0; c < 4; ++c)
        oacc[c] = __builtin_amdgcn_mfma_f32_16x16x32_bf16(vr[ks][c], pf, oacc[c], 0, 0, 0);
    }
    __builtin_amdgcn_s_setprio(0);
    if(kc + 1 < nc){
      asm volatile("s_waitcnt vmcnt(0)");
      __syncthreads();
      cur ^= 1;
    }
  }

  float scale = (1.f / lsum) * gateT[((size_t)bh << 10) + q];
  #pragma unroll
  for(int c = 0; c < 4; ++c)
    #pragma unroll
    for(int i = 0; i < 4; i += 2){
      u32 p = pack2(oacc[c][i]*scale, oacc[c][i+1]*scale);
      *(u32*)&ot[w][l15][c*16 + g*4 + i] = p;
    }
  int r = lane >> 2, c4 = lane & 3;
  uint4 v0 = *(uint4*)&ot[w][r][c4*16];
  uint4 v1 = *(uint4*)&ot[w][r][c4*16 + 8];
  u16* op = out + ((size_t)(b*S + qt*16 + r))*D + h*DK + c4*16;
  *(uint4*)op = v0;
  *(uint4*)(op + 8) = v1;
}

} // namespace

extern "C" void kernel_launch(void* const* d_in, const int* in_sizes, int n_in,
                              void* d_out, int out_size, void* d_ws, size_t ws_size,
                              hipStream_t stream){
  (void)in_sizes; (void)n_in; (void)out_size; (void)ws_size;
  const float* states = (const float*)d_in[0];
  const int*   ids    = (const int*)d_in[1];
  float* xout = (float*)d_out;

  char* w = (char*)d_ws;
  u16* wbf[10];
  for(int i = 0; i < 10; ++i){ wbf[i] = (u16*)w; w += (size_t)1024*1024*2; }
  u16* wsm[4];
  for(int i = 0; i < 4; ++i){ wsm[i] = (u16*)w; w += (size_t)16*1024*2; }
  u16* xln  = (u16*)w; w += (size_t)2048*1024*2;
  u16* qb   = (u16*)w; w += (size_t)2048*1024*2;
  u16* kb   = (u16*)w; w += (size_t)2048*1024*2;
  u16* vt   = (u16*)w; w += (size_t)2048*1024*2;
  u16* attn = (u16*)w; w += (size_t)2048*1024*2;
  float* gateT  = (float*)w; w += (size_t)2048*16*4;
  float* aprojT = (float*)w; w += (size_t)2048*16*4;
  int* segd = (int*)w;

  // big weights: l0 qw4 kw6 vw8 ow12 | l1 vw17 ow21 | l2 qw25 kw27 vw29 ow33
  const int widx[10] = {4, 6, 8, 12, 17, 21, 25, 27, 29, 33};
  // small head mats: l0 gw10, l1 gw19, l2 gw31, l1 aw16
  const int sidx[4] = {10, 19, 31, 16};
  CvtArgs ca = {};
  for(int i = 0; i < 10; ++i){ ca.src[i] = (const float*)d_in[widx[i]]; ca.dst[i] = wbf[i]; }
  for(int i = 0; i < 4; ++i){ ca.src[10+i] = (const float*)d_in[sidx[i]]; ca.dst[10+i] = wsm[i]; }

  dim3 b256(256);
  // prologue: cvt(5152) + seg(2) + ln0(2048)
  prologue_kernel<<<dim3(7202), b256, 0, stream>>>(ca, ids, segd,
      states, (const float*)d_in[2], (const float*)d_in[3], xln);

  // ---- layer 0: SDPA, self bias
  proj_sdpa_kernel<<<dim3(512), b256, 0, stream>>>(xln, wbf[0], wbf[1], wbf[2],
      (const float*)d_in[5], (const float*)d_in[7], (const float*)d_in[9], qb, kb, vt,
      wsm[0], (const float*)d_in[11], gateT);
  attn4_kernel<0><<<dim3(512), b256, 0, stream>>>(qb, kb, vt, nullptr, segd, gateT, attn);
  oproj_kernel<<<dim3(256), b256, 0, stream>>>(attn, wbf[3], (const float*)d_in[13], xout, states);

  // ---- layer 1: pool, self bias
  ln_kernel<<<dim3(2048), b256, 0, stream>>>(xout, (const float*)d_in[14], (const float*)d_in[15], xln);
  proj_pool_kernel<<<dim3(384), b256, 0, stream>>>(xln, wbf[4], (const float*)d_in[18], vt,
      wsm[1], (const float*)d_in[20], gateT, wsm[3], aprojT);
  attn4_kernel<2><<<dim3(512), b256, 0, stream>>>(nullptr, nullptr, vt, aprojT, segd, gateT, attn);
  oproj_kernel<<<dim3(256), b256, 0, stream>>>(attn, wbf[5], (const float*)d_in[22], xout, xout);

  // ---- layer 2: SDPA, cross bias
  ln_kernel<<<dim3(2048), b256, 0, stream>>>(xout, (const float*)d_in[23], (const float*)d_in[24], xln);
  proj_sdpa_kernel<<<dim3(512), b256, 0, stream>>>(xln, wbf[6], wbf[7], wbf[8],
      (const float*)d_in[26], (const float*)d_in[28], (const float*)d_in[30], qb, kb, vt,
      wsm[2], (const float*)d_in[32], gateT);
  attn4_kernel<1><<<dim3(512), b256, 0, stream>>>(qb, kb, vt, nullptr, segd, gateT, attn);
  oproj_kernel<<<dim3(256), b256, 0, stream>>>(attn, wbf[9], (const float*)d_in[34], xout, xout);
}